// Round 1
// baseline (2819.336 us; speedup 1.0000x reference)
//
#include <hip/hip_runtime.h>
#include <cmath>

#define BB 8
#define LL 512
#define DD 1024
#define HH 16
#define HDD 64
#define FFD 4096
#define MTOK (BB*LL)
#define EPSF 1e-5f

// scalar slot map (ws floats 0..63):
// 0..5: weight absmax (q,k,v,o,fc,pj)
// 6,7 q hi/neg pass1 | 8,9 k1 | 10,11 v1 | 12,13 q2 | 14,15 k2 | 16,17 v2
// 18: attn max prob | 19,20 o | 21,22 fc | 23,24 pj

__device__ inline void atomicMaxPos(float* addr, float v) {
  atomicMax((unsigned int*)addr, __float_as_uint(v));  // valid for v >= 0, slot init 0
}

__global__ void k_init(float* __restrict__ s) { s[threadIdx.x] = 0.0f; }

__global__ void k_absmax(const float* __restrict__ w, int n4, float* __restrict__ slot) {
  const float4* w4 = (const float4*)w;
  float m = 0.0f;
  for (int i = blockIdx.x * blockDim.x + threadIdx.x; i < n4; i += gridDim.x * blockDim.x) {
    float4 v = w4[i];
    m = fmaxf(m, fmaxf(fmaxf(fabsf(v.x), fabsf(v.y)), fmaxf(fabsf(v.z), fabsf(v.w))));
  }
  #pragma unroll
  for (int o = 32; o; o >>= 1) m = fmaxf(m, __shfl_down(m, o, 64));
  __shared__ float sb[4];
  int lane = threadIdx.x & 63, wid = threadIdx.x >> 6;
  if (lane == 0) sb[wid] = m;
  __syncthreads();
  if (threadIdx.x == 0) atomicMaxPos(slot, fmaxf(fmaxf(sb[0], sb[1]), fmaxf(sb[2], sb[3])));
}

__global__ void k_minmax(const float* __restrict__ x, int n4,
                         float* __restrict__ sHi, float* __restrict__ sNeg) {
  const float4* x4 = (const float4*)x;
  float hi = 0.0f, ng = 0.0f;  // clamped at 0: matches jnp.maximum(max,0)/minimum(min,0)
  for (int i = blockIdx.x * blockDim.x + threadIdx.x; i < n4; i += gridDim.x * blockDim.x) {
    float4 v = x4[i];
    hi = fmaxf(hi, fmaxf(fmaxf(v.x, v.y), fmaxf(v.z, v.w)));
    ng = fmaxf(ng, fmaxf(fmaxf(-v.x, -v.y), fmaxf(-v.z, -v.w)));
  }
  #pragma unroll
  for (int o = 32; o; o >>= 1) {
    hi = fmaxf(hi, __shfl_down(hi, o, 64));
    ng = fmaxf(ng, __shfl_down(ng, o, 64));
  }
  __shared__ float sh[4], sn[4];
  int lane = threadIdx.x & 63, wid = threadIdx.x >> 6;
  if (lane == 0) { sh[wid] = hi; sn[wid] = ng; }
  __syncthreads();
  if (threadIdx.x == 0) {
    atomicMaxPos(sHi, fmaxf(fmaxf(sh[0], sh[1]), fmaxf(sh[2], sh[3])));
    atomicMaxPos(sNeg, fmaxf(fmaxf(sn[0], sn[1]), fmaxf(sn[2], sn[3])));
  }
}

__global__ void k_quantw(const float* __restrict__ w, float* __restrict__ wq, int n4,
                         const float* __restrict__ slot) {
  float s = fmaxf(*slot / 127.0f, 1e-8f);
  const float4* w4 = (const float4*)w;
  float4* q4 = (float4*)wq;
  for (int i = blockIdx.x * blockDim.x + threadIdx.x; i < n4; i += gridDim.x * blockDim.x) {
    float4 v = w4[i];
    v.x = fminf(fmaxf(rintf(v.x / s), -128.0f), 127.0f) * s;
    v.y = fminf(fmaxf(rintf(v.y / s), -128.0f), 127.0f) * s;
    v.z = fminf(fmaxf(rintf(v.z / s), -128.0f), 127.0f) * s;
    v.w = fminf(fmaxf(rintf(v.w / s), -128.0f), 127.0f) * s;
    q4[i] = v;
  }
}

__device__ inline float2 fq_params(const float* sHi, const float* sNeg) {
  float hi = *sHi, lo = -(*sNeg);
  float scale = fmaxf((hi - lo) / 255.0f, 1e-8f);
  float zp = rintf(-lo / scale);
  return make_float2(scale, zp);
}
__device__ inline float fq1(float x, float scale, float zp) {
  float q = fminf(fmaxf(rintf(x / scale) + zp, 0.0f), 255.0f);
  return (q - zp) * scale;
}

__global__ void k_quant(float* __restrict__ x, int n4,
                        const float* __restrict__ sHi, const float* __restrict__ sNeg) {
  float2 p = fq_params(sHi, sNeg);
  float4* x4 = (float4*)x;
  for (int i = blockIdx.x * blockDim.x + threadIdx.x; i < n4; i += gridDim.x * blockDim.x) {
    float4 v = x4[i];
    v.x = fq1(v.x, p.x, p.y); v.y = fq1(v.y, p.x, p.y);
    v.z = fq1(v.z, p.x, p.y); v.w = fq1(v.w, p.x, p.y);
    x4[i] = v;
  }
}

__global__ void k_quant_res(const float* __restrict__ lin, const float* __restrict__ res,
                            float* __restrict__ out, int n4,
                            const float* __restrict__ sHi, const float* __restrict__ sNeg) {
  float2 p = fq_params(sHi, sNeg);
  const float4* l4 = (const float4*)lin;
  const float4* r4 = (const float4*)res;
  float4* o4 = (float4*)out;
  for (int i = blockIdx.x * blockDim.x + threadIdx.x; i < n4; i += gridDim.x * blockDim.x) {
    float4 v = l4[i]; float4 r = r4[i]; float4 o;
    o.x = r.x + fq1(v.x, p.x, p.y); o.y = r.y + fq1(v.y, p.x, p.y);
    o.z = r.z + fq1(v.z, p.x, p.y); o.w = r.w + fq1(v.w, p.x, p.y);
    o4[i] = o;
  }
}

__device__ inline float gelu_exact(float g) {
  return 0.5f * g * (1.0f + erff(g * 0.7071067811865475f));
}

__global__ void k_quant_gelu(float* __restrict__ x, int n4,
                             const float* __restrict__ sHi, const float* __restrict__ sNeg) {
  float2 p = fq_params(sHi, sNeg);
  float4* x4 = (float4*)x;
  for (int i = blockIdx.x * blockDim.x + threadIdx.x; i < n4; i += gridDim.x * blockDim.x) {
    float4 v = x4[i];
    v.x = gelu_exact(fq1(v.x, p.x, p.y)); v.y = gelu_exact(fq1(v.y, p.x, p.y));
    v.z = gelu_exact(fq1(v.z, p.x, p.y)); v.w = gelu_exact(fq1(v.w, p.x, p.y));
    x4[i] = v;
  }
}

__device__ inline float block_sum256(float v, float* sb) {
  #pragma unroll
  for (int o = 32; o; o >>= 1) v += __shfl_down(v, o, 64);
  int lane = threadIdx.x & 63, wid = threadIdx.x >> 6;
  __syncthreads();
  if (lane == 0) sb[wid] = v;
  __syncthreads();
  return sb[0] + sb[1] + sb[2] + sb[3];
}

__global__ __launch_bounds__(256) void k_ln(const float* __restrict__ x, const float* __restrict__ g,
                                            const float* __restrict__ bta, float* __restrict__ out) {
  __shared__ float sb[4];
  int row = blockIdx.x;
  const float4* xr = (const float4*)(x + (size_t)row * DD);
  float4 v = xr[threadIdx.x];
  float mu = block_sum256(v.x + v.y + v.z + v.w, sb) * (1.0f / DD);
  float dx = v.x - mu, dy = v.y - mu, dz = v.z - mu, dw = v.w - mu;
  float var = block_sum256(dx*dx + dy*dy + dz*dz + dw*dw, sb) * (1.0f / DD);
  float rs = 1.0f / sqrtf(var + EPSF);
  float4 gv = ((const float4*)g)[threadIdx.x];
  float4 bv = ((const float4*)bta)[threadIdx.x];
  float4 o;
  o.x = dx * rs * gv.x + bv.x;
  o.y = dy * rs * gv.y + bv.y;
  o.z = dz * rs * gv.z + bv.z;
  o.w = dw * rs * gv.w + bv.w;
  ((float4*)(out + (size_t)row * DD))[threadIdx.x] = o;
}

// C[4096,N] = A[4096,K] . Bw[N,K]^T + bias[N], fp32, 128x128x8 tiles, 8x8 microtile
__global__ __launch_bounds__(256) void k_gemm(const float* __restrict__ A, const float* __restrict__ Bw,
                                              const float* __restrict__ bias, float* __restrict__ C,
                                              int N, int K) {
  __shared__ float As[8][128];
  __shared__ float Bs[8][128];
  const int t = threadIdx.x;
  const int tx = t & 15, ty = t >> 4;
  const int row0 = blockIdx.y * 128, col0 = blockIdx.x * 128;
  const int lm = t >> 1, lk = (t & 1) * 4;
  const float* Ap = A + (size_t)(row0 + lm) * K + lk;
  const float* Bp = Bw + (size_t)(col0 + lm) * K + lk;
  float acc[8][8];
  #pragma unroll
  for (int i = 0; i < 8; ++i)
    #pragma unroll
    for (int j = 0; j < 8; ++j) acc[i][j] = 0.0f;

  for (int k0 = 0; k0 < K; k0 += 8) {
    float4 av = *(const float4*)(Ap + k0);
    float4 bv = *(const float4*)(Bp + k0);
    __syncthreads();
    As[lk][lm] = av.x; As[lk+1][lm] = av.y; As[lk+2][lm] = av.z; As[lk+3][lm] = av.w;
    Bs[lk][lm] = bv.x; Bs[lk+1][lm] = bv.y; Bs[lk+2][lm] = bv.z; Bs[lk+3][lm] = bv.w;
    __syncthreads();
    #pragma unroll
    for (int kk = 0; kk < 8; ++kk) {
      float a[8], bb[8];
      #pragma unroll
      for (int i = 0; i < 8; ++i) a[i] = As[kk][ty*8 + i];
      #pragma unroll
      for (int j = 0; j < 8; ++j) bb[j] = Bs[kk][tx*8 + j];
      #pragma unroll
      for (int i = 0; i < 8; ++i)
        #pragma unroll
        for (int j = 0; j < 8; ++j) acc[i][j] += a[i] * bb[j];
    }
  }
  #pragma unroll
  for (int i = 0; i < 8; ++i) {
    int r = row0 + ty*8 + i;
    float* Cr = C + (size_t)r * N + col0 + tx*8;
    const float* br = bias + col0 + tx*8;
    float4 o0, o1;
    o0.x = acc[i][0] + br[0]; o0.y = acc[i][1] + br[1];
    o0.z = acc[i][2] + br[2]; o0.w = acc[i][3] + br[3];
    o1.x = acc[i][4] + br[4]; o1.y = acc[i][5] + br[5];
    o1.z = acc[i][6] + br[6]; o1.w = acc[i][7] + br[7];
    *(float4*)Cr = o0; *(float4*)(Cr + 4) = o1;
  }
}

// Attention phase A: per-row softmax stats (m, Z) + global max prob via atomicMax(1/Z)
__global__ __launch_bounds__(256) void k_attn_a(const float* __restrict__ qb, const float* __restrict__ kb,
                                                float* __restrict__ rowm, float* __restrict__ rowz,
                                                float* __restrict__ maxp) {
  const int l0 = blockIdx.x * 32, h = blockIdx.y, b = blockIdx.z;
  __shared__ float qs[32][68];
  __shared__ float ks[64][68];
  const int t = threadIdx.x;
  const float* qbase = qb + ((size_t)(b*LL + l0)) * DD + h*HDD;
  for (int s = t; s < 512; s += 256) {
    int r = s >> 4, d4 = (s & 15) * 4;
    *(float4*)&qs[r][d4] = *(const float4*)(qbase + (size_t)r * DD + d4);
  }
  const int r = t >> 3, ml = t & 7;
  const float* kbase = kb + ((size_t)(b*LL)) * DD + h*HDD;
  float mrun = -INFINITY, zrun = 0.0f;
  for (int c = 0; c < 8; ++c) {
    __syncthreads();
    for (int s = t; s < 1024; s += 256) {
      int mm = s >> 4, d4 = (s & 15) * 4;
      *(float4*)&ks[mm][d4] = *(const float4*)(kbase + (size_t)(c*64 + mm) * DD + d4);
    }
    __syncthreads();
    float acc8[8] = {0,0,0,0,0,0,0,0};
    #pragma unroll
    for (int d4 = 0; d4 < 64; d4 += 4) {
      float4 qv = *(const float4*)&qs[r][d4];
      #pragma unroll
      for (int j = 0; j < 8; ++j) {
        float4 kv = *(const float4*)&ks[ml + 8*j][d4];
        acc8[j] += qv.x*kv.x + qv.y*kv.y + qv.z*kv.z + qv.w*kv.w;
      }
    }
    float sj[8];
    #pragma unroll
    for (int j = 0; j < 8; ++j) sj[j] = acc8[j] * 0.125f;
    float newm = mrun;
    #pragma unroll
    for (int j = 0; j < 8; ++j) newm = fmaxf(newm, sj[j]);
    zrun *= expf(mrun - newm);
    #pragma unroll
    for (int j = 0; j < 8; ++j) zrun += expf(sj[j] - newm);
    mrun = newm;
  }
  #pragma unroll
  for (int o = 1; o < 8; o <<= 1) {
    float om = __shfl_xor(mrun, o, 64);
    float oz = __shfl_xor(zrun, o, 64);
    float nm = fmaxf(mrun, om);
    zrun = zrun * expf(mrun - nm) + oz * expf(om - nm);
    mrun = nm;
  }
  if (ml == 0) {
    int rid = (b*HH + h) * LL + l0 + r;
    rowm[rid] = mrun; rowz[rid] = zrun;
    atomicMaxPos(maxp, 1.0f / zrun);
  }
}

// Attention phase B: recompute scores, quantize probs (zp=0), ctx = Pq @ V
__global__ __launch_bounds__(256) void k_attn_b(const float* __restrict__ qb, const float* __restrict__ kb,
                                                const float* __restrict__ vb,
                                                const float* __restrict__ rowm, const float* __restrict__ rowz,
                                                const float* __restrict__ maxp, float* __restrict__ ctx) {
  const int l0 = blockIdx.x * 32, h = blockIdx.y, b = blockIdx.z;
  __shared__ float qs[32][68];
  __shared__ float ks[64][68];
  __shared__ float vs[64][68];
  __shared__ float ps[32][68];
  const int t = threadIdx.x;
  const float scale = fmaxf(*maxp / 255.0f, 1e-8f);
  const float* qbase = qb + ((size_t)(b*LL + l0)) * DD + h*HDD;
  for (int s = t; s < 512; s += 256) {
    int r = s >> 4, d4 = (s & 15) * 4;
    *(float4*)&qs[r][d4] = *(const float4*)(qbase + (size_t)r * DD + d4);
  }
  const int r = t >> 3, ml = t & 7;
  const int rid = (b*HH + h) * LL + l0 + r;
  const float rmv = rowm[rid], rzv = rowz[rid];
  const int dcol = t & 63, rb = (t >> 6) * 8;
  float acc[8] = {0,0,0,0,0,0,0,0};
  const float* kbase = kb + ((size_t)(b*LL)) * DD + h*HDD;
  const float* vbase = vb + ((size_t)(b*LL)) * DD + h*HDD;
  for (int c = 0; c < 8; ++c) {
    __syncthreads();
    for (int s = t; s < 1024; s += 256) {
      int mm = s >> 4, d4 = (s & 15) * 4;
      *(float4*)&ks[mm][d4] = *(const float4*)(kbase + (size_t)(c*64 + mm) * DD + d4);
      *(float4*)&vs[mm][d4] = *(const float4*)(vbase + (size_t)(c*64 + mm) * DD + d4);
    }
    __syncthreads();
    float acc8[8] = {0,0,0,0,0,0,0,0};
    #pragma unroll
    for (int d4 = 0; d4 < 64; d4 += 4) {
      float4 qv = *(const float4*)&qs[r][d4];
      #pragma unroll
      for (int j = 0; j < 8; ++j) {
        float4 kv = *(const float4*)&ks[ml + 8*j][d4];
        acc8[j] += qv.x*kv.x + qv.y*kv.y + qv.z*kv.z + qv.w*kv.w;
      }
    }
    #pragma unroll
    for (int j = 0; j < 8; ++j) {
      float sc = acc8[j] * 0.125f;
      float p = expf(sc - rmv) / rzv;
      float q = fminf(fmaxf(rintf(p / scale), 0.0f), 255.0f);
      ps[r][ml + 8*j] = q * scale;
    }
    __syncthreads();
    #pragma unroll
    for (int m4 = 0; m4 < 64; m4 += 4) {
      float v0 = vs[m4][dcol], v1 = vs[m4+1][dcol], v2 = vs[m4+2][dcol], v3 = vs[m4+3][dcol];
      #pragma unroll
      for (int i = 0; i < 8; ++i) {
        float4 pv = *(const float4*)&ps[rb + i][m4];
        acc[i] += pv.x*v0 + pv.y*v1 + pv.z*v2 + pv.w*v3;
      }
    }
  }
  #pragma unroll
  for (int i = 0; i < 8; ++i)
    ctx[((size_t)(b*LL + l0 + rb + i)) * DD + h*HDD + dcol] = acc[i];
}

extern "C" void kernel_launch(void* const* d_in, const int* in_sizes, int n_in,
                              void* d_out, int out_size, void* d_ws, size_t ws_size,
                              hipStream_t stream) {
  const float* x    = (const float*)d_in[0];
  const float* ln1g = (const float*)d_in[1];
  const float* ln1b = (const float*)d_in[2];
  const float* wq   = (const float*)d_in[3];
  const float* bq   = (const float*)d_in[4];
  const float* wk   = (const float*)d_in[5];
  const float* bk   = (const float*)d_in[6];
  const float* wv   = (const float*)d_in[7];
  const float* bv   = (const float*)d_in[8];
  const float* wo   = (const float*)d_in[9];
  const float* bo   = (const float*)d_in[10];
  const float* ln2g = (const float*)d_in[11];
  const float* ln2b = (const float*)d_in[12];
  const float* wfc  = (const float*)d_in[13];
  const float* bfc  = (const float*)d_in[14];
  const float* wpj  = (const float*)d_in[15];
  const float* bpj  = (const float*)d_in[16];
  float* out = (float*)d_out;
  float* ws = (float*)d_ws;

  size_t off = 0;
  float* scal = ws + off; off += 256;
  float* wqQ  = ws + off; off += (size_t)DD*DD;
  float* wkQ  = ws + off; off += (size_t)DD*DD;
  float* wvQ  = ws + off; off += (size_t)DD*DD;
  float* woQ  = ws + off; off += (size_t)DD*DD;
  float* wfcQ = ws + off; off += (size_t)FFD*DD;
  float* wpjQ = ws + off; off += (size_t)DD*FFD;
  float* hbuf = ws + off; off += (size_t)MTOK*DD;   // h, later o_lin
  float* qb   = ws + off; off += (size_t)MTOK*DD;   // q, later h2
  float* kb   = ws + off; off += (size_t)MTOK*DD;
  float* vb   = ws + off; off += (size_t)MTOK*DD;   // v, later proj_lin
  float* rowm = ws + off; off += (size_t)BB*HH*LL;
  float* rowz = ws + off; off += (size_t)BB*HH*LL;
  float* ctxb = ws + off; off += (size_t)MTOK*DD;
  float* x1   = ws + off; off += (size_t)MTOK*DD;
  float* fcb  = ws + off; off += (size_t)MTOK*FFD;

  const int ND  = MTOK*DD/4;    // 1048576 float4s
  const int NF  = MTOK*FFD/4;
  const int NW  = DD*DD/4;
  const int NWF = DD*FFD/4;

  auto g4 = [](int n4){ int g = (n4 + 255) / 256; return g > 4096 ? 4096 : g; };

  k_init<<<1, 64, 0, stream>>>(scal);

  k_absmax<<<1024, 256, 0, stream>>>(wq,  NW,  scal+0);
  k_absmax<<<1024, 256, 0, stream>>>(wk,  NW,  scal+1);
  k_absmax<<<1024, 256, 0, stream>>>(wv,  NW,  scal+2);
  k_absmax<<<1024, 256, 0, stream>>>(wo,  NW,  scal+3);
  k_absmax<<<2048, 256, 0, stream>>>(wfc, NWF, scal+4);
  k_absmax<<<2048, 256, 0, stream>>>(wpj, NWF, scal+5);

  k_quantw<<<g4(NW),  256, 0, stream>>>(wq,  wqQ,  NW,  scal+0);
  k_quantw<<<g4(NW),  256, 0, stream>>>(wk,  wkQ,  NW,  scal+1);
  k_quantw<<<g4(NW),  256, 0, stream>>>(wv,  wvQ,  NW,  scal+2);
  k_quantw<<<g4(NW),  256, 0, stream>>>(wo,  woQ,  NW,  scal+3);
  k_quantw<<<g4(NWF), 256, 0, stream>>>(wfc, wfcQ, NWF, scal+4);
  k_quantw<<<g4(NWF), 256, 0, stream>>>(wpj, wpjQ, NWF, scal+5);

  k_ln<<<MTOK, 256, 0, stream>>>(x, ln1g, ln1b, hbuf);

  k_gemm<<<dim3(8, 32), 256, 0, stream>>>(hbuf, wqQ, bq, qb, DD, DD);
  k_gemm<<<dim3(8, 32), 256, 0, stream>>>(hbuf, wkQ, bk, kb, DD, DD);
  k_gemm<<<dim3(8, 32), 256, 0, stream>>>(hbuf, wvQ, bv, vb, DD, DD);

  // double fake-quant (qlinear output fq + post-heads fq)
  k_minmax<<<2048, 256, 0, stream>>>(qb, ND, scal+6,  scal+7);
  k_quant <<<g4(ND), 256, 0, stream>>>(qb, ND, scal+6,  scal+7);
  k_minmax<<<2048, 256, 0, stream>>>(qb, ND, scal+12, scal+13);
  k_quant <<<g4(ND), 256, 0, stream>>>(qb, ND, scal+12, scal+13);
  k_minmax<<<2048, 256, 0, stream>>>(kb, ND, scal+8,  scal+9);
  k_quant <<<g4(ND), 256, 0, stream>>>(kb, ND, scal+8,  scal+9);
  k_minmax<<<2048, 256, 0, stream>>>(kb, ND, scal+14, scal+15);
  k_quant <<<g4(ND), 256, 0, stream>>>(kb, ND, scal+14, scal+15);
  k_minmax<<<2048, 256, 0, stream>>>(vb, ND, scal+10, scal+11);
  k_quant <<<g4(ND), 256, 0, stream>>>(vb, ND, scal+10, scal+11);
  k_minmax<<<2048, 256, 0, stream>>>(vb, ND, scal+16, scal+17);
  k_quant <<<g4(ND), 256, 0, stream>>>(vb, ND, scal+16, scal+17);

  k_attn_a<<<dim3(16, 16, 8), 256, 0, stream>>>(qb, kb, rowm, rowz, scal+18);
  k_attn_b<<<dim3(16, 16, 8), 256, 0, stream>>>(qb, kb, vb, rowm, rowz, scal+18, ctxb);

  k_gemm<<<dim3(8, 32), 256, 0, stream>>>(ctxb, woQ, bo, hbuf, DD, DD);
  k_minmax<<<2048, 256, 0, stream>>>(hbuf, ND, scal+19, scal+20);
  k_quant_res<<<g4(ND), 256, 0, stream>>>(hbuf, x, x1, ND, scal+19, scal+20);

  k_ln<<<MTOK, 256, 0, stream>>>(x1, ln2g, ln2b, qb);
  k_gemm<<<dim3(32, 32), 256, 0, stream>>>(qb, wfcQ, bfc, fcb, FFD, DD);
  k_minmax<<<2048, 256, 0, stream>>>(fcb, NF, scal+21, scal+22);
  k_quant_gelu<<<g4(NF), 256, 0, stream>>>(fcb, NF, scal+21, scal+22);

  k_gemm<<<dim3(8, 32), 256, 0, stream>>>(fcb, wpjQ, bpj, vb, DD, FFD);
  k_minmax<<<2048, 256, 0, stream>>>(vb, ND, scal+23, scal+24);
  k_quant_res<<<g4(ND), 256, 0, stream>>>(vb, x1, out, ND, scal+23, scal+24);
}

// Round 2
// 1647.706 us; speedup vs baseline: 1.7111x; 1.7111x over previous
//
#include <hip/hip_runtime.h>
#include <cmath>

#define BB 8
#define LL 512
#define DD 1024
#define HH 16
#define HDD 64
#define FFD 4096
#define MTOK (BB*LL)
#define EPSF 1e-5f

typedef __attribute__((ext_vector_type(8))) short bf16x8;
typedef __attribute__((ext_vector_type(4))) float f32x4;

// scalar slot map (ws floats 0..63):
// 0..5: weight absmax (q,k,v,o,fc,pj)
// 6,7 q hi/neg pass1 | 8,9 k1 | 10,11 v1 | 12,13 q2 | 14,15 k2 | 16,17 v2
// 18: attn max prob | 19,20 o | 21,22 fc | 23,24 pj

__device__ inline void atomicMaxPos(float* addr, float v) {
  atomicMax((unsigned int*)addr, __float_as_uint(v));  // valid for v >= 0, slot init 0
}

__device__ inline unsigned short f2bf(float x) {  // RNE truncate to bf16 bits (no nan/inf in data)
  unsigned int u = __float_as_uint(x);
  u += 0x7fffu + ((u >> 16) & 1u);
  return (unsigned short)(u >> 16);
}
__device__ inline float bf2f(unsigned short h) {
  return __uint_as_float((unsigned int)h << 16);
}

__global__ void k_init(float* __restrict__ s) { s[threadIdx.x] = 0.0f; }

__global__ void k_absmax(const float* __restrict__ w, int n4, float* __restrict__ slot) {
  const float4* w4 = (const float4*)w;
  float m = 0.0f;
  for (int i = blockIdx.x * blockDim.x + threadIdx.x; i < n4; i += gridDim.x * blockDim.x) {
    float4 v = w4[i];
    m = fmaxf(m, fmaxf(fmaxf(fabsf(v.x), fabsf(v.y)), fmaxf(fabsf(v.z), fabsf(v.w))));
  }
  #pragma unroll
  for (int o = 32; o; o >>= 1) m = fmaxf(m, __shfl_down(m, o, 64));
  __shared__ float sb[4];
  int lane = threadIdx.x & 63, wid = threadIdx.x >> 6;
  if (lane == 0) sb[wid] = m;
  __syncthreads();
  if (threadIdx.x == 0) atomicMaxPos(slot, fmaxf(fmaxf(sb[0], sb[1]), fmaxf(sb[2], sb[3])));
}

__global__ void k_minmax(const float* __restrict__ x, int n4,
                         float* __restrict__ sHi, float* __restrict__ sNeg) {
  const float4* x4 = (const float4*)x;
  float hi = 0.0f, ng = 0.0f;  // clamped at 0: matches jnp.maximum(max,0)/minimum(min,0)
  for (int i = blockIdx.x * blockDim.x + threadIdx.x; i < n4; i += gridDim.x * blockDim.x) {
    float4 v = x4[i];
    hi = fmaxf(hi, fmaxf(fmaxf(v.x, v.y), fmaxf(v.z, v.w)));
    ng = fmaxf(ng, fmaxf(fmaxf(-v.x, -v.y), fmaxf(-v.z, -v.w)));
  }
  #pragma unroll
  for (int o = 32; o; o >>= 1) {
    hi = fmaxf(hi, __shfl_down(hi, o, 64));
    ng = fmaxf(ng, __shfl_down(ng, o, 64));
  }
  __shared__ float sh[4], sn[4];
  int lane = threadIdx.x & 63, wid = threadIdx.x >> 6;
  if (lane == 0) { sh[wid] = hi; sn[wid] = ng; }
  __syncthreads();
  if (threadIdx.x == 0) {
    atomicMaxPos(sHi, fmaxf(fmaxf(sh[0], sh[1]), fmaxf(sh[2], sh[3])));
    atomicMaxPos(sNeg, fmaxf(fmaxf(sn[0], sn[1]), fmaxf(sn[2], sn[3])));
  }
}

// weights -> bf16 INTEGER codes (qint in [-128,127]), exact in bf16; scale applied in GEMM epilogue
__global__ void k_quantw_bf(const float* __restrict__ w, unsigned short* __restrict__ wq, int n4,
                            const float* __restrict__ slot) {
  float s = fmaxf(*slot / 127.0f, 1e-8f);
  const float4* w4 = (const float4*)w;
  ushort4* q4 = (ushort4*)wq;
  for (int i = blockIdx.x * blockDim.x + threadIdx.x; i < n4; i += gridDim.x * blockDim.x) {
    float4 v = w4[i];
    ushort4 o;
    o.x = f2bf(fminf(fmaxf(rintf(v.x / s), -128.0f), 127.0f));
    o.y = f2bf(fminf(fmaxf(rintf(v.y / s), -128.0f), 127.0f));
    o.z = f2bf(fminf(fmaxf(rintf(v.z / s), -128.0f), 127.0f));
    o.w = f2bf(fminf(fmaxf(rintf(v.w / s), -128.0f), 127.0f));
    q4[i] = o;
  }
}

__device__ inline float2 fq_params(const float* sHi, const float* sNeg) {
  float hi = *sHi, lo = -(*sNeg);
  float scale = fmaxf((hi - lo) / 255.0f, 1e-8f);
  float zp = rintf(-lo / scale);
  return make_float2(scale, zp);
}
__device__ inline float fq1(float x, float scale, float zp) {
  float q = fminf(fmaxf(rintf(x / scale) + zp, 0.0f), 255.0f);
  return (q - zp) * scale;
}

__global__ void k_quant(float* __restrict__ x, int n4,
                        const float* __restrict__ sHi, const float* __restrict__ sNeg) {
  float2 p = fq_params(sHi, sNeg);
  float4* x4 = (float4*)x;
  for (int i = blockIdx.x * blockDim.x + threadIdx.x; i < n4; i += gridDim.x * blockDim.x) {
    float4 v = x4[i];
    v.x = fq1(v.x, p.x, p.y); v.y = fq1(v.y, p.x, p.y);
    v.z = fq1(v.z, p.x, p.y); v.w = fq1(v.w, p.x, p.y);
    x4[i] = v;
  }
}

__global__ void k_quant_res(const float* __restrict__ lin, const float* __restrict__ res,
                            float* __restrict__ out, int n4,
                            const float* __restrict__ sHi, const float* __restrict__ sNeg) {
  float2 p = fq_params(sHi, sNeg);
  const float4* l4 = (const float4*)lin;
  const float4* r4 = (const float4*)res;
  float4* o4 = (float4*)out;
  for (int i = blockIdx.x * blockDim.x + threadIdx.x; i < n4; i += gridDim.x * blockDim.x) {
    float4 v = l4[i]; float4 r = r4[i]; float4 o;
    o.x = r.x + fq1(v.x, p.x, p.y); o.y = r.y + fq1(v.y, p.x, p.y);
    o.z = r.z + fq1(v.z, p.x, p.y); o.w = r.w + fq1(v.w, p.x, p.y);
    o4[i] = o;
  }
}

__device__ inline float gelu_exact(float g) {
  return 0.5f * g * (1.0f + erff(g * 0.7071067811865475f));
}

__global__ void k_quant_gelu(float* __restrict__ x, int n4,
                             const float* __restrict__ sHi, const float* __restrict__ sNeg) {
  float2 p = fq_params(sHi, sNeg);
  float4* x4 = (float4*)x;
  for (int i = blockIdx.x * blockDim.x + threadIdx.x; i < n4; i += gridDim.x * blockDim.x) {
    float4 v = x4[i];
    v.x = gelu_exact(fq1(v.x, p.x, p.y)); v.y = gelu_exact(fq1(v.y, p.x, p.y));
    v.z = gelu_exact(fq1(v.z, p.x, p.y)); v.w = gelu_exact(fq1(v.w, p.x, p.y));
    x4[i] = v;
  }
}

__device__ inline float block_sum256(float v, float* sb) {
  #pragma unroll
  for (int o = 32; o; o >>= 1) v += __shfl_down(v, o, 64);
  int lane = threadIdx.x & 63, wid = threadIdx.x >> 6;
  __syncthreads();
  if (lane == 0) sb[wid] = v;
  __syncthreads();
  return sb[0] + sb[1] + sb[2] + sb[3];
}

__global__ __launch_bounds__(256) void k_ln(const float* __restrict__ x, const float* __restrict__ g,
                                            const float* __restrict__ bta, float* __restrict__ out) {
  __shared__ float sb[4];
  int row = blockIdx.x;
  const float4* xr = (const float4*)(x + (size_t)row * DD);
  float4 v = xr[threadIdx.x];
  float mu = block_sum256(v.x + v.y + v.z + v.w, sb) * (1.0f / DD);
  float dx = v.x - mu, dy = v.y - mu, dz = v.z - mu, dw = v.w - mu;
  float var = block_sum256(dx*dx + dy*dy + dz*dz + dw*dw, sb) * (1.0f / DD);
  float rs = 1.0f / sqrtf(var + EPSF);
  float4 gv = ((const float4*)g)[threadIdx.x];
  float4 bv = ((const float4*)bta)[threadIdx.x];
  float4 o;
  o.x = dx * rs * gv.x + bv.x;
  o.y = dy * rs * gv.y + bv.y;
  o.z = dz * rs * gv.z + bv.z;
  o.w = dw * rs * gv.w + bv.w;
  ((float4*)(out + (size_t)row * DD))[threadIdx.x] = o;
}

// MFMA GEMM: C[M=4096,N] = scale * (A[M,K] @ Bq[N,K]^T) + bias[N]
// A fp32 -> split hi/lo bf16 (2 MFMAs, near-fp32 accuracy); Bq = exact bf16 integer codes.
// 128x128 tile, 4 waves of 64x64, mfma_f32_16x16x32_bf16. LDS stride 40 (free 2-way conflicts only).
#define LSTR 40
__global__ __launch_bounds__(256) void k_gemm_mfma(
    const float* __restrict__ A, const unsigned short* __restrict__ Bq,
    const float* __restrict__ bias, const float* __restrict__ wscale,
    float* __restrict__ C, int N, int K) {
  __shared__ unsigned short Ahi[128 * LSTR];
  __shared__ unsigned short Alo[128 * LSTR];
  __shared__ unsigned short Bsm[128 * LSTR];
  const int t = threadIdx.x;
  const int row0 = blockIdx.y * 128, col0 = blockIdx.x * 128;
  const int wave = t >> 6, lane = t & 63;
  const int wr = (wave >> 1) * 64, wc = (wave & 1) * 64;
  const int fr = lane & 15;   // A-row / B-col within 16-tile
  const int fq = lane >> 4;   // quad: k-offset = fq*8, C-row = fq*4+reg
  const float s = fmaxf(wscale[0] / 127.0f, 1e-8f);

  f32x4 acc[4][4];
  #pragma unroll
  for (int i = 0; i < 4; ++i)
    #pragma unroll
    for (int j = 0; j < 4; ++j) acc[i][j] = (f32x4){0.f, 0.f, 0.f, 0.f};

  for (int k0 = 0; k0 < K; k0 += 32) {
    __syncthreads();
    // stage A: 128 rows x 32 fp32 -> hi/lo bf16
    #pragma unroll
    for (int it = 0; it < 4; ++it) {
      int si = t + it * 256;
      int r = si >> 3, k4 = (si & 7) * 4;
      float4 v = *(const float4*)(A + (size_t)(row0 + r) * K + k0 + k4);
      ushort4 h, l;
      h.x = f2bf(v.x); l.x = f2bf(v.x - bf2f(h.x));
      h.y = f2bf(v.y); l.y = f2bf(v.y - bf2f(h.y));
      h.z = f2bf(v.z); l.z = f2bf(v.z - bf2f(h.z));
      h.w = f2bf(v.w); l.w = f2bf(v.w - bf2f(h.w));
      *(ushort4*)&Ahi[r * LSTR + k4] = h;
      *(ushort4*)&Alo[r * LSTR + k4] = l;
    }
    // stage B: 128 rows x 32 bf16
    #pragma unroll
    for (int it = 0; it < 2; ++it) {
      int si = t + it * 256;
      int r = si >> 2, k8 = (si & 3) * 8;
      bf16x8 v = *(const bf16x8*)(Bq + (size_t)(col0 + r) * K + k0 + k8);
      *(bf16x8*)&Bsm[r * LSTR + k8] = v;
    }
    __syncthreads();

    bf16x8 ah[4], al[4], bfg[4];
    #pragma unroll
    for (int i = 0; i < 4; ++i) {
      int ar = wr + i * 16 + fr;
      ah[i]  = *(const bf16x8*)&Ahi[ar * LSTR + fq * 8];
      al[i]  = *(const bf16x8*)&Alo[ar * LSTR + fq * 8];
      int br = wc + i * 16 + fr;
      bfg[i] = *(const bf16x8*)&Bsm[br * LSTR + fq * 8];
    }
    #pragma unroll
    for (int i = 0; i < 4; ++i)
      #pragma unroll
      for (int j = 0; j < 4; ++j) {
        acc[i][j] = __builtin_amdgcn_mfma_f32_16x16x32_bf16(ah[i], bfg[j], acc[i][j], 0, 0, 0);
        acc[i][j] = __builtin_amdgcn_mfma_f32_16x16x32_bf16(al[i], bfg[j], acc[i][j], 0, 0, 0);
      }
  }

  // epilogue: C/D layout col = lane&15, row = (lane>>4)*4 + reg
  #pragma unroll
  for (int i = 0; i < 4; ++i) {
    #pragma unroll
    for (int j = 0; j < 4; ++j) {
      int col = col0 + wc + j * 16 + fr;
      float bcol = bias[col];
      #pragma unroll
      for (int rg = 0; rg < 4; ++rg) {
        int row = row0 + wr + i * 16 + fq * 4 + rg;
        C[(size_t)row * N + col] = acc[i][j][rg] * s + bcol;
      }
    }
  }
}

// Attention phase A: per-row softmax stats (m, Z) + global max prob via atomicMax(1/Z)
__global__ __launch_bounds__(256) void k_attn_a(const float* __restrict__ qb, const float* __restrict__ kb,
                                                float* __restrict__ rowm, float* __restrict__ rowz,
                                                float* __restrict__ maxp) {
  const int l0 = blockIdx.x * 32, h = blockIdx.y, b = blockIdx.z;
  __shared__ float qs[32][68];
  __shared__ float ks[64][68];
  const int t = threadIdx.x;
  const float* qbase = qb + ((size_t)(b*LL + l0)) * DD + h*HDD;
  for (int s = t; s < 512; s += 256) {
    int r = s >> 4, d4 = (s & 15) * 4;
    *(float4*)&qs[r][d4] = *(const float4*)(qbase + (size_t)r * DD + d4);
  }
  const int r = t >> 3, ml = t & 7;
  const float* kbase = kb + ((size_t)(b*LL)) * DD + h*HDD;
  float mrun = -INFINITY, zrun = 0.0f;
  for (int c = 0; c < 8; ++c) {
    __syncthreads();
    for (int s = t; s < 1024; s += 256) {
      int mm = s >> 4, d4 = (s & 15) * 4;
      *(float4*)&ks[mm][d4] = *(const float4*)(kbase + (size_t)(c*64 + mm) * DD + d4);
    }
    __syncthreads();
    float acc8[8] = {0,0,0,0,0,0,0,0};
    #pragma unroll
    for (int d4 = 0; d4 < 64; d4 += 4) {
      float4 qv = *(const float4*)&qs[r][d4];
      #pragma unroll
      for (int j = 0; j < 8; ++j) {
        float4 kv = *(const float4*)&ks[ml + 8*j][d4];
        acc8[j] += qv.x*kv.x + qv.y*kv.y + qv.z*kv.z + qv.w*kv.w;
      }
    }
    float sj[8];
    #pragma unroll
    for (int j = 0; j < 8; ++j) sj[j] = acc8[j] * 0.125f;
    float newm = mrun;
    #pragma unroll
    for (int j = 0; j < 8; ++j) newm = fmaxf(newm, sj[j]);
    zrun *= expf(mrun - newm);
    #pragma unroll
    for (int j = 0; j < 8; ++j) zrun += expf(sj[j] - newm);
    mrun = newm;
  }
  #pragma unroll
  for (int o = 1; o < 8; o <<= 1) {
    float om = __shfl_xor(mrun, o, 64);
    float oz = __shfl_xor(zrun, o, 64);
    float nm = fmaxf(mrun, om);
    zrun = zrun * expf(mrun - nm) + oz * expf(om - nm);
    mrun = nm;
  }
  if (ml == 0) {
    int rid = (b*HH + h) * LL + l0 + r;
    rowm[rid] = mrun; rowz[rid] = zrun;
    atomicMaxPos(maxp, 1.0f / zrun);
  }
}

// Attention phase B: recompute scores, quantize probs (zp=0), ctx = Pq @ V
__global__ __launch_bounds__(256) void k_attn_b(const float* __restrict__ qb, const float* __restrict__ kb,
                                                const float* __restrict__ vb,
                                                const float* __restrict__ rowm, const float* __restrict__ rowz,
                                                const float* __restrict__ maxp, float* __restrict__ ctx) {
  const int l0 = blockIdx.x * 32, h = blockIdx.y, b = blockIdx.z;
  __shared__ float qs[32][68];
  __shared__ float ks[64][68];
  __shared__ float vs[64][68];
  __shared__ float ps[32][68];
  const int t = threadIdx.x;
  const float scale = fmaxf(*maxp / 255.0f, 1e-8f);
  const float* qbase = qb + ((size_t)(b*LL + l0)) * DD + h*HDD;
  for (int s = t; s < 512; s += 256) {
    int r = s >> 4, d4 = (s & 15) * 4;
    *(float4*)&qs[r][d4] = *(const float4*)(qbase + (size_t)r * DD + d4);
  }
  const int r = t >> 3, ml = t & 7;
  const int rid = (b*HH + h) * LL + l0 + r;
  const float rmv = rowm[rid], rzv = rowz[rid];
  const int dcol = t & 63, rb = (t >> 6) * 8;
  float acc[8] = {0,0,0,0,0,0,0,0};
  const float* kbase = kb + ((size_t)(b*LL)) * DD + h*HDD;
  const float* vbase = vb + ((size_t)(b*LL)) * DD + h*HDD;
  for (int c = 0; c < 8; ++c) {
    __syncthreads();
    for (int s = t; s < 1024; s += 256) {
      int mm = s >> 4, d4 = (s & 15) * 4;
      *(float4*)&ks[mm][d4] = *(const float4*)(kbase + (size_t)(c*64 + mm) * DD + d4);
      *(float4*)&vs[mm][d4] = *(const float4*)(vbase + (size_t)(c*64 + mm) * DD + d4);
    }
    __syncthreads();
    float acc8[8] = {0,0,0,0,0,0,0,0};
    #pragma unroll
    for (int d4 = 0; d4 < 64; d4 += 4) {
      float4 qv = *(const float4*)&qs[r][d4];
      #pragma unroll
      for (int j = 0; j < 8; ++j) {
        float4 kv = *(const float4*)&ks[ml + 8*j][d4];
        acc8[j] += qv.x*kv.x + qv.y*kv.y + qv.z*kv.z + qv.w*kv.w;
      }
    }
    #pragma unroll
    for (int j = 0; j < 8; ++j) {
      float sc = acc8[j] * 0.125f;
      float p = expf(sc - rmv) / rzv;
      float q = fminf(fmaxf(rintf(p / scale), 0.0f), 255.0f);
      ps[r][ml + 8*j] = q * scale;
    }
    __syncthreads();
    #pragma unroll
    for (int m4 = 0; m4 < 64; m4 += 4) {
      float v0 = vs[m4][dcol], v1 = vs[m4+1][dcol], v2 = vs[m4+2][dcol], v3 = vs[m4+3][dcol];
      #pragma unroll
      for (int i = 0; i < 8; ++i) {
        float4 pv = *(const float4*)&ps[rb + i][m4];
        acc[i] += pv.x*v0 + pv.y*v1 + pv.z*v2 + pv.w*v3;
      }
    }
  }
  #pragma unroll
  for (int i = 0; i < 8; ++i)
    ctx[((size_t)(b*LL + l0 + rb + i)) * DD + h*HDD + dcol] = acc[i];
}

extern "C" void kernel_launch(void* const* d_in, const int* in_sizes, int n_in,
                              void* d_out, int out_size, void* d_ws, size_t ws_size,
                              hipStream_t stream) {
  const float* x    = (const float*)d_in[0];
  const float* ln1g = (const float*)d_in[1];
  const float* ln1b = (const float*)d_in[2];
  const float* wq   = (const float*)d_in[3];
  const float* bq   = (const float*)d_in[4];
  const float* wk   = (const float*)d_in[5];
  const float* bk   = (const float*)d_in[6];
  const float* wv   = (const float*)d_in[7];
  const float* bv   = (const float*)d_in[8];
  const float* wo   = (const float*)d_in[9];
  const float* bo   = (const float*)d_in[10];
  const float* ln2g = (const float*)d_in[11];
  const float* ln2b = (const float*)d_in[12];
  const float* wfc  = (const float*)d_in[13];
  const float* bfc  = (const float*)d_in[14];
  const float* wpj  = (const float*)d_in[15];
  const float* bpj  = (const float*)d_in[16];
  float* out = (float*)d_out;
  float* ws = (float*)d_ws;

  size_t off = 0;
  float* scal = ws + off; off += 256;
  unsigned short* wqQ  = (unsigned short*)(ws + off); off += (size_t)DD*DD/2;
  unsigned short* wkQ  = (unsigned short*)(ws + off); off += (size_t)DD*DD/2;
  unsigned short* wvQ  = (unsigned short*)(ws + off); off += (size_t)DD*DD/2;
  unsigned short* woQ  = (unsigned short*)(ws + off); off += (size_t)DD*DD/2;
  unsigned short* wfcQ = (unsigned short*)(ws + off); off += (size_t)FFD*DD/2;
  unsigned short* wpjQ = (unsigned short*)(ws + off); off += (size_t)DD*FFD/2;
  float* hbuf = ws + off; off += (size_t)MTOK*DD;   // h, later o_lin
  float* qb   = ws + off; off += (size_t)MTOK*DD;   // q, later h2
  float* kb   = ws + off; off += (size_t)MTOK*DD;
  float* vb   = ws + off; off += (size_t)MTOK*DD;   // v, later proj_lin
  float* rowm = ws + off; off += (size_t)BB*HH*LL;
  float* rowz = ws + off; off += (size_t)BB*HH*LL;
  float* ctxb = ws + off; off += (size_t)MTOK*DD;
  float* x1   = ws + off; off += (size_t)MTOK*DD;
  float* fcb  = ws + off; off += (size_t)MTOK*FFD;

  const int ND  = MTOK*DD/4;
  const int NF  = MTOK*FFD/4;
  const int NW  = DD*DD/4;
  const int NWF = DD*FFD/4;

  auto g4 = [](int n4){ int g = (n4 + 255) / 256; return g > 4096 ? 4096 : g; };

  k_init<<<1, 64, 0, stream>>>(scal);

  k_absmax<<<1024, 256, 0, stream>>>(wq,  NW,  scal+0);
  k_absmax<<<1024, 256, 0, stream>>>(wk,  NW,  scal+1);
  k_absmax<<<1024, 256, 0, stream>>>(wv,  NW,  scal+2);
  k_absmax<<<1024, 256, 0, stream>>>(wo,  NW,  scal+3);
  k_absmax<<<2048, 256, 0, stream>>>(wfc, NWF, scal+4);
  k_absmax<<<2048, 256, 0, stream>>>(wpj, NWF, scal+5);

  k_quantw_bf<<<g4(NW),  256, 0, stream>>>(wq,  wqQ,  NW,  scal+0);
  k_quantw_bf<<<g4(NW),  256, 0, stream>>>(wk,  wkQ,  NW,  scal+1);
  k_quantw_bf<<<g4(NW),  256, 0, stream>>>(wv,  wvQ,  NW,  scal+2);
  k_quantw_bf<<<g4(NW),  256, 0, stream>>>(wo,  woQ,  NW,  scal+3);
  k_quantw_bf<<<g4(NWF), 256, 0, stream>>>(wfc, wfcQ, NWF, scal+4);
  k_quantw_bf<<<g4(NWF), 256, 0, stream>>>(wpj, wpjQ, NWF, scal+5);

  k_ln<<<MTOK, 256, 0, stream>>>(x, ln1g, ln1b, hbuf);

  k_gemm_mfma<<<dim3(8, 32), 256, 0, stream>>>(hbuf, wqQ, bq, scal+0, qb, DD, DD);
  k_gemm_mfma<<<dim3(8, 32), 256, 0, stream>>>(hbuf, wkQ, bk, scal+1, kb, DD, DD);
  k_gemm_mfma<<<dim3(8, 32), 256, 0, stream>>>(hbuf, wvQ, bv, scal+2, vb, DD, DD);

  // double fake-quant (qlinear output fq + post-heads fq)
  k_minmax<<<2048, 256, 0, stream>>>(qb, ND, scal+6,  scal+7);
  k_quant <<<g4(ND), 256, 0, stream>>>(qb, ND, scal+6,  scal+7);
  k_minmax<<<2048, 256, 0, stream>>>(qb, ND, scal+12, scal+13);
  k_quant <<<g4(ND), 256, 0, stream>>>(qb, ND, scal+12, scal+13);
  k_minmax<<<2048, 256, 0, stream>>>(kb, ND, scal+8,  scal+9);
  k_quant <<<g4(ND), 256, 0, stream>>>(kb, ND, scal+8,  scal+9);
  k_minmax<<<2048, 256, 0, stream>>>(kb, ND, scal+14, scal+15);
  k_quant <<<g4(ND), 256, 0, stream>>>(kb, ND, scal+14, scal+15);
  k_minmax<<<2048, 256, 0, stream>>>(vb, ND, scal+10, scal+11);
  k_quant <<<g4(ND), 256, 0, stream>>>(vb, ND, scal+10, scal+11);
  k_minmax<<<2048, 256, 0, stream>>>(vb, ND, scal+16, scal+17);
  k_quant <<<g4(ND), 256, 0, stream>>>(vb, ND, scal+16, scal+17);

  k_attn_a<<<dim3(16, 16, 8), 256, 0, stream>>>(qb, kb, rowm, rowz, scal+18);
  k_attn_b<<<dim3(16, 16, 8), 256, 0, stream>>>(qb, kb, vb, rowm, rowz, scal+18, ctxb);

  k_gemm_mfma<<<dim3(8, 32), 256, 0, stream>>>(ctxb, woQ, bo, scal+3, hbuf, DD, DD);
  k_minmax<<<2048, 256, 0, stream>>>(hbuf, ND, scal+19, scal+20);
  k_quant_res<<<g4(ND), 256, 0, stream>>>(hbuf, x, x1, ND, scal+19, scal+20);

  k_ln<<<MTOK, 256, 0, stream>>>(x1, ln2g, ln2b, qb);
  k_gemm_mfma<<<dim3(32, 32), 256, 0, stream>>>(qb, wfcQ, bfc, scal+4, fcb, FFD, DD);
  k_minmax<<<2048, 256, 0, stream>>>(fcb, NF, scal+21, scal+22);
  k_quant_gelu<<<g4(NF), 256, 0, stream>>>(fcb, NF, scal+21, scal+22);

  k_gemm_mfma<<<dim3(8, 32), 256, 0, stream>>>(fcb, wpjQ, bpj, scal+5, vb, DD, FFD);
  k_minmax<<<2048, 256, 0, stream>>>(vb, ND, scal+23, scal+24);
  k_quant_res<<<g4(ND), 256, 0, stream>>>(vb, x1, out, ND, scal+23, scal+24);
}

// Round 3
// 872.039 us; speedup vs baseline: 3.2330x; 1.8895x over previous
//
#include <hip/hip_runtime.h>
#include <cmath>

#define BB 8
#define LL 512
#define DD 1024
#define HH 16
#define HDD 64
#define FFD 4096
#define MTOK (BB*LL)
#define EPSF 1e-5f

typedef __attribute__((ext_vector_type(8))) short bf16x8;
typedef __attribute__((ext_vector_type(4))) float f32x4;

// scalar slots: 0..5 weight absmax (q,k,v,o,fc,pj)
// 6,7 q lin hi/neg | 8,9 k | 10,11 v | 18 maxp | 19,20 o | 21,22 fc | 23,24 pj

__device__ inline void atomicMaxPos(float* addr, float v) {
  atomicMax((unsigned int*)addr, __float_as_uint(v));  // v >= 0, slot init 0
}

__device__ inline unsigned short f2bf(float x) {  // RNE to bf16 bits
  unsigned int u = __float_as_uint(x);
  u += 0x7fffu + ((u >> 16) & 1u);
  return (unsigned short)(u >> 16);
}
__device__ inline float bf2f(unsigned short h) {
  return __uint_as_float((unsigned int)h << 16);
}

__global__ void k_init(float* __restrict__ s) { s[threadIdx.x] = 0.0f; }

__global__ void k_absmax(const float* __restrict__ w, int n4, float* __restrict__ slot) {
  const float4* w4 = (const float4*)w;
  float m = 0.0f;
  for (int i = blockIdx.x * blockDim.x + threadIdx.x; i < n4; i += gridDim.x * blockDim.x) {
    float4 v = w4[i];
    m = fmaxf(m, fmaxf(fmaxf(fabsf(v.x), fabsf(v.y)), fmaxf(fabsf(v.z), fabsf(v.w))));
  }
  #pragma unroll
  for (int o = 32; o; o >>= 1) m = fmaxf(m, __shfl_down(m, o, 64));
  __shared__ float sb[4];
  int lane = threadIdx.x & 63, wid = threadIdx.x >> 6;
  if (lane == 0) sb[wid] = m;
  __syncthreads();
  if (threadIdx.x == 0) atomicMaxPos(slot, fmaxf(fmaxf(sb[0], sb[1]), fmaxf(sb[2], sb[3])));
}

// weights -> bf16 INTEGER codes (qint in [-128,127]); scale applied in GEMM epilogue
__global__ void k_quantw_bf(const float* __restrict__ w, unsigned short* __restrict__ wq, int n4,
                            const float* __restrict__ slot) {
  float s = fmaxf(*slot / 127.0f, 1e-8f);
  const float4* w4 = (const float4*)w;
  ushort4* q4 = (ushort4*)wq;
  for (int i = blockIdx.x * blockDim.x + threadIdx.x; i < n4; i += gridDim.x * blockDim.x) {
    float4 v = w4[i];
    ushort4 o;
    o.x = f2bf(fminf(fmaxf(rintf(v.x / s), -128.0f), 127.0f));
    o.y = f2bf(fminf(fmaxf(rintf(v.y / s), -128.0f), 127.0f));
    o.z = f2bf(fminf(fmaxf(rintf(v.z / s), -128.0f), 127.0f));
    o.w = f2bf(fminf(fmaxf(rintf(v.w / s), -128.0f), 127.0f));
    q4[i] = o;
  }
}

__device__ inline float2 fq_params(const float* sHi, const float* sNeg) {
  float hi = *sHi, lo = -(*sNeg);
  float scale = fmaxf((hi - lo) / 255.0f, 1e-8f);
  float zp = rintf(-lo / scale);
  return make_float2(scale, zp);
}
__device__ inline float fq1(float x, float scale, float zp) {
  float q = fminf(fmaxf(rintf(x / scale) + zp, 0.0f), 255.0f);
  return (q - zp) * scale;
}
// pass-2 observer params are fq(pass-1 extremes) by monotonicity — no scan needed
__device__ inline float2 fq_params2(const float* sHi, const float* sNeg) {
  float2 p1 = fq_params(sHi, sNeg);
  float hi2 = fq1(*sHi, p1.x, p1.y);      // >= 0
  float lo2 = fq1(-(*sNeg), p1.x, p1.y);  // <= 0
  float scale = fmaxf((hi2 - lo2) / 255.0f, 1e-8f);
  float zp = rintf(-lo2 / scale);
  return make_float2(scale, zp);
}
__device__ inline float code2(float x, float2 p1, float2 p2) {  // double-fq -> integer code
  float v1 = fq1(x, p1.x, p1.y);
  float q = fminf(fmaxf(rintf(v1 / p2.x) + p2.y, 0.0f), 255.0f);
  return q - p2.y;  // in [-255,255], exact bf16
}

// raw linear out -> double fake-quant -> bf16 integer codes (token-major)
__global__ void k_quant_codes(const float* __restrict__ x, unsigned short* __restrict__ oc, int n4,
                              const float* __restrict__ sl) {
  float2 p1 = fq_params(sl, sl + 1);
  float2 p2 = fq_params2(sl, sl + 1);
  const float4* x4 = (const float4*)x;
  ushort4* o4 = (ushort4*)oc;
  for (int i = blockIdx.x * blockDim.x + threadIdx.x; i < n4; i += gridDim.x * blockDim.x) {
    float4 v = x4[i];
    ushort4 o;
    o.x = f2bf(code2(v.x, p1, p2)); o.y = f2bf(code2(v.y, p1, p2));
    o.z = f2bf(code2(v.z, p1, p2)); o.w = f2bf(code2(v.w, p1, p2));
    o4[i] = o;
  }
}

// V variant: codes written per-head TRANSPOSED: vt[((b*H+h)*64+d)*512 + m]
__global__ __launch_bounds__(256) void k_quant_codes_vt(
    const float* __restrict__ vraw, unsigned short* __restrict__ vt,
    const float* __restrict__ sl) {
  __shared__ unsigned short tile[64 * 68];
  float2 p1 = fq_params(sl, sl + 1);
  float2 p2 = fq_params2(sl, sl + 1);
  const int m0 = blockIdx.x * 64, h = blockIdx.y, b = blockIdx.z;
  const int t = threadIdx.x;
  const int r = t >> 2, c0 = (t & 3) * 16;
  const float* src = vraw + ((size_t)(b * LL + m0 + r)) * DD + h * HDD + c0;
  #pragma unroll
  for (int i = 0; i < 4; ++i) {
    float4 v = *(const float4*)(src + i * 4);
    ushort4 o;
    o.x = f2bf(code2(v.x, p1, p2)); o.y = f2bf(code2(v.y, p1, p2));
    o.z = f2bf(code2(v.z, p1, p2)); o.w = f2bf(code2(v.w, p1, p2));
    *(ushort4*)&tile[r * 68 + c0 + i * 4] = o;
  }
  __syncthreads();
  const int dr = t >> 2, ms = (t & 3) * 16;
  unsigned short* dst = vt + ((size_t)((b * HH + h) * HDD + dr)) * LL + m0 + ms;
  #pragma unroll
  for (int i = 0; i < 4; ++i) {
    ushort4 o;
    o.x = tile[(ms + i * 4 + 0) * 68 + dr];
    o.y = tile[(ms + i * 4 + 1) * 68 + dr];
    o.z = tile[(ms + i * 4 + 2) * 68 + dr];
    o.w = tile[(ms + i * 4 + 3) * 68 + dr];
    *(ushort4*)(dst + i * 4) = o;
  }
}

__global__ void k_quant_res(const float* __restrict__ lin, const float* __restrict__ res,
                            float* __restrict__ out, int n4,
                            const float* __restrict__ sHi, const float* __restrict__ sNeg) {
  float2 p = fq_params(sHi, sNeg);
  const float4* l4 = (const float4*)lin;
  const float4* r4 = (const float4*)res;
  float4* o4 = (float4*)out;
  for (int i = blockIdx.x * blockDim.x + threadIdx.x; i < n4; i += gridDim.x * blockDim.x) {
    float4 v = l4[i]; float4 r = r4[i]; float4 o;
    o.x = r.x + fq1(v.x, p.x, p.y); o.y = r.y + fq1(v.y, p.x, p.y);
    o.z = r.z + fq1(v.z, p.x, p.y); o.w = r.w + fq1(v.w, p.x, p.y);
    o4[i] = o;
  }
}

__device__ inline float gelu_exact(float g) {
  return 0.5f * g * (1.0f + erff(g * 0.7071067811865475f));
}

__global__ void k_quant_gelu(float* __restrict__ x, int n4,
                             const float* __restrict__ sHi, const float* __restrict__ sNeg) {
  float2 p = fq_params(sHi, sNeg);
  float4* x4 = (float4*)x;
  for (int i = blockIdx.x * blockDim.x + threadIdx.x; i < n4; i += gridDim.x * blockDim.x) {
    float4 v = x4[i];
    v.x = gelu_exact(fq1(v.x, p.x, p.y)); v.y = gelu_exact(fq1(v.y, p.x, p.y));
    v.z = gelu_exact(fq1(v.z, p.x, p.y)); v.w = gelu_exact(fq1(v.w, p.x, p.y));
    x4[i] = v;
  }
}

__device__ inline float block_sum256(float v, float* sb) {
  #pragma unroll
  for (int o = 32; o; o >>= 1) v += __shfl_down(v, o, 64);
  int lane = threadIdx.x & 63, wid = threadIdx.x >> 6;
  __syncthreads();
  if (lane == 0) sb[wid] = v;
  __syncthreads();
  return sb[0] + sb[1] + sb[2] + sb[3];
}

__global__ __launch_bounds__(256) void k_ln(const float* __restrict__ x, const float* __restrict__ g,
                                            const float* __restrict__ bta, float* __restrict__ out) {
  __shared__ float sb[4];
  int row = blockIdx.x;
  const float4* xr = (const float4*)(x + (size_t)row * DD);
  float4 v = xr[threadIdx.x];
  float mu = block_sum256(v.x + v.y + v.z + v.w, sb) * (1.0f / DD);
  float dx = v.x - mu, dy = v.y - mu, dz = v.z - mu, dw = v.w - mu;
  float var = block_sum256(dx*dx + dy*dy + dz*dz + dw*dw, sb) * (1.0f / DD);
  float rs = 1.0f / sqrtf(var + EPSF);
  float4 gv = ((const float4*)g)[threadIdx.x];
  float4 bv = ((const float4*)bta)[threadIdx.x];
  float4 o;
  o.x = dx * rs * gv.x + bv.x;
  o.y = dy * rs * gv.y + bv.y;
  o.z = dz * rs * gv.z + bv.z;
  o.w = dw * rs * gv.w + bv.w;
  ((float4*)(out + (size_t)row * DD))[threadIdx.x] = o;
}

// MFMA GEMM: C[4096,N] = scale*(A[M,K] @ Bq[N,K]^T) + bias[N]; epilogue-fused minmax observer.
#define LSTR 40
__global__ __launch_bounds__(256) void k_gemm_mfma(
    const float* __restrict__ A, const unsigned short* __restrict__ Bq,
    const float* __restrict__ bias, const float* __restrict__ wscale,
    float* __restrict__ C, int N, int K,
    float* __restrict__ oHi, float* __restrict__ oNeg) {
  __shared__ unsigned short Ahi[128 * LSTR];
  __shared__ unsigned short Alo[128 * LSTR];
  __shared__ unsigned short Bsm[128 * LSTR];
  __shared__ float redH, redN;
  const int t = threadIdx.x;
  const int row0 = blockIdx.y * 128, col0 = blockIdx.x * 128;
  const int wave = t >> 6, lane = t & 63;
  const int wr = (wave >> 1) * 64, wc = (wave & 1) * 64;
  const int fr = lane & 15;
  const int fq = lane >> 4;
  const float s = fmaxf(wscale[0] / 127.0f, 1e-8f);
  if (t == 0) { redH = 0.f; redN = 0.f; }

  f32x4 acc[4][4];
  #pragma unroll
  for (int i = 0; i < 4; ++i)
    #pragma unroll
    for (int j = 0; j < 4; ++j) acc[i][j] = (f32x4){0.f, 0.f, 0.f, 0.f};

  for (int k0 = 0; k0 < K; k0 += 32) {
    __syncthreads();
    #pragma unroll
    for (int it = 0; it < 4; ++it) {
      int si = t + it * 256;
      int r = si >> 3, k4 = (si & 7) * 4;
      float4 v = *(const float4*)(A + (size_t)(row0 + r) * K + k0 + k4);
      ushort4 h, l;
      h.x = f2bf(v.x); l.x = f2bf(v.x - bf2f(h.x));
      h.y = f2bf(v.y); l.y = f2bf(v.y - bf2f(h.y));
      h.z = f2bf(v.z); l.z = f2bf(v.z - bf2f(h.z));
      h.w = f2bf(v.w); l.w = f2bf(v.w - bf2f(h.w));
      *(ushort4*)&Ahi[r * LSTR + k4] = h;
      *(ushort4*)&Alo[r * LSTR + k4] = l;
    }
    #pragma unroll
    for (int it = 0; it < 2; ++it) {
      int si = t + it * 256;
      int r = si >> 2, k8 = (si & 3) * 8;
      bf16x8 v = *(const bf16x8*)(Bq + (size_t)(col0 + r) * K + k0 + k8);
      *(bf16x8*)&Bsm[r * LSTR + k8] = v;
    }
    __syncthreads();

    bf16x8 ah[4], al[4], bfg[4];
    #pragma unroll
    for (int i = 0; i < 4; ++i) {
      int ar = wr + i * 16 + fr;
      ah[i]  = *(const bf16x8*)&Ahi[ar * LSTR + fq * 8];
      al[i]  = *(const bf16x8*)&Alo[ar * LSTR + fq * 8];
      int br = wc + i * 16 + fr;
      bfg[i] = *(const bf16x8*)&Bsm[br * LSTR + fq * 8];
    }
    #pragma unroll
    for (int i = 0; i < 4; ++i)
      #pragma unroll
      for (int j = 0; j < 4; ++j) {
        acc[i][j] = __builtin_amdgcn_mfma_f32_16x16x32_bf16(ah[i], bfg[j], acc[i][j], 0, 0, 0);
        acc[i][j] = __builtin_amdgcn_mfma_f32_16x16x32_bf16(al[i], bfg[j], acc[i][j], 0, 0, 0);
      }
  }

  float ohi = 0.f, ong = 0.f;
  #pragma unroll
  for (int i = 0; i < 4; ++i) {
    #pragma unroll
    for (int j = 0; j < 4; ++j) {
      int col = col0 + wc + j * 16 + fr;
      float bcol = bias[col];
      #pragma unroll
      for (int rg = 0; rg < 4; ++rg) {
        int row = row0 + wr + i * 16 + fq * 4 + rg;
        float val = acc[i][j][rg] * s + bcol;
        ohi = fmaxf(ohi, val); ong = fmaxf(ong, -val);
        C[(size_t)row * N + col] = val;
      }
    }
  }
  #pragma unroll
  for (int o = 32; o; o >>= 1) {
    ohi = fmaxf(ohi, __shfl_down(ohi, o, 64));
    ong = fmaxf(ong, __shfl_down(ong, o, 64));
  }
  if (lane == 0) { atomicMaxPos(&redH, ohi); atomicMaxPos(&redN, ong); }
  __syncthreads();
  if (t == 0) { atomicMaxPos(oHi, redH); atomicMaxPos(oNeg, redN); }
}

// ---- MFMA attention on integer bf16 codes ----
// Phase A: row softmax stats (m,Z in scaled-score units) + global max prob = max(1/Z)
__global__ __launch_bounds__(256) void k_attn_a_mfma(
    const unsigned short* __restrict__ qc, const unsigned short* __restrict__ kc,
    const float* __restrict__ slq, const float* __restrict__ slk,
    float* __restrict__ rowm, float* __restrict__ rowz, float* __restrict__ maxp) {
  __shared__ unsigned short ks[64 * 72];
  __shared__ float redp;
  const int t = threadIdx.x, wave = t >> 6, lane = t & 63;
  const int fr = lane & 15, fq = lane >> 4;
  const int l0 = blockIdx.x * 64, h = blockIdx.y, b = blockIdx.z;
  const float sfac = fq_params2(slq, slq + 1).x * fq_params2(slk, slk + 1).x * 0.125f;
  if (t == 0) redp = 0.f;
  const unsigned short* qrow = qc + ((size_t)(b * LL + l0 + wave * 16 + fr)) * DD + h * HDD;
  bf16x8 qa0 = *(const bf16x8*)(qrow + fq * 8);
  bf16x8 qa1 = *(const bf16x8*)(qrow + 32 + fq * 8);
  float mrun[4] = {-INFINITY, -INFINITY, -INFINITY, -INFINITY};
  float zrun[4] = {0.f, 0.f, 0.f, 0.f};
  for (int mc = 0; mc < LL; mc += 64) {
    __syncthreads();
    #pragma unroll
    for (int it = 0; it < 2; ++it) {
      int si = t + it * 256, r = si >> 3, c8 = (si & 7) * 8;
      *(bf16x8*)&ks[r * 72 + c8] =
          *(const bf16x8*)(kc + ((size_t)(b * LL + mc + r)) * DD + h * HDD + c8);
    }
    __syncthreads();
    float sv[4][4];
    #pragma unroll
    for (int j = 0; j < 4; ++j) {
      bf16x8 b0 = *(const bf16x8*)&ks[(j * 16 + fr) * 72 + fq * 8];
      bf16x8 b1 = *(const bf16x8*)&ks[(j * 16 + fr) * 72 + 32 + fq * 8];
      f32x4 sAcc = (f32x4){0.f, 0.f, 0.f, 0.f};
      sAcc = __builtin_amdgcn_mfma_f32_16x16x32_bf16(qa0, b0, sAcc, 0, 0, 0);
      sAcc = __builtin_amdgcn_mfma_f32_16x16x32_bf16(qa1, b1, sAcc, 0, 0, 0);
      #pragma unroll
      for (int rg = 0; rg < 4; ++rg) sv[j][rg] = sAcc[rg] * sfac;
    }
    #pragma unroll
    for (int rg = 0; rg < 4; ++rg) {
      float nm = mrun[rg];
      #pragma unroll
      for (int j = 0; j < 4; ++j) nm = fmaxf(nm, sv[j][rg]);
      float z = zrun[rg] * expf(mrun[rg] - nm);
      #pragma unroll
      for (int j = 0; j < 4; ++j) z += expf(sv[j][rg] - nm);
      zrun[rg] = z; mrun[rg] = nm;
    }
  }
  #pragma unroll
  for (int off = 1; off < 16; off <<= 1) {
    #pragma unroll
    for (int rg = 0; rg < 4; ++rg) {
      float om = __shfl_xor(mrun[rg], off, 64);
      float oz = __shfl_xor(zrun[rg], off, 64);
      float nm = fmaxf(mrun[rg], om);
      zrun[rg] = zrun[rg] * expf(mrun[rg] - nm) + oz * expf(om - nm);
      mrun[rg] = nm;
    }
  }
  if (fr == 0) {
    int rid = (b * HH + h) * LL + l0 + wave * 16 + fq * 4;
    float lmax = 0.f;
    #pragma unroll
    for (int rg = 0; rg < 4; ++rg) {
      rowm[rid + rg] = mrun[rg]; rowz[rid + rg] = zrun[rg];
      lmax = fmaxf(lmax, 1.0f / zrun[rg]);
    }
    atomicMaxPos(&redp, lmax);
  }
  __syncthreads();
  if (t == 0) atomicMaxPos(maxp, redp);
}

// Phase B: recompute S, quantize P -> bf16 codes via LDS C->A layout roundtrip, ctx = P@V (MFMA)
__global__ __launch_bounds__(256) void k_attn_b_mfma(
    const unsigned short* __restrict__ qc, const unsigned short* __restrict__ kc,
    const unsigned short* __restrict__ vt,
    const float* __restrict__ slq, const float* __restrict__ slk, const float* __restrict__ slv,
    const float* __restrict__ rowm, const float* __restrict__ rowz,
    const float* __restrict__ maxp, float* __restrict__ ctx) {
  __shared__ unsigned short ks[64 * 72];
  __shared__ unsigned short vs[64 * 72];
  __shared__ unsigned short ps[4][16 * 72];
  const int t = threadIdx.x, wave = t >> 6, lane = t & 63;
  const int fr = lane & 15, fq = lane >> 4;
  const int l0 = blockIdx.x * 64, h = blockIdx.y, b = blockIdx.z;
  const float sfac = fq_params2(slq, slq + 1).x * fq_params2(slk, slk + 1).x * 0.125f;
  const float sv2 = fq_params2(slv, slv + 1).x;
  const float pscale = fmaxf(maxp[0] / 255.0f, 1e-8f);
  const float ipscale = 1.0f / pscale;
  const int ridb = (b * HH + h) * LL + l0 + wave * 16 + fq * 4;
  float rm[4], rzi[4];
  #pragma unroll
  for (int rg = 0; rg < 4; ++rg) { rm[rg] = rowm[ridb + rg]; rzi[rg] = 1.0f / rowz[ridb + rg]; }
  const unsigned short* qrow = qc + ((size_t)(b * LL + l0 + wave * 16 + fr)) * DD + h * HDD;
  bf16x8 qa0 = *(const bf16x8*)(qrow + fq * 8);
  bf16x8 qa1 = *(const bf16x8*)(qrow + 32 + fq * 8);
  f32x4 acc[4];
  #pragma unroll
  for (int jd = 0; jd < 4; ++jd) acc[jd] = (f32x4){0.f, 0.f, 0.f, 0.f};

  for (int mc = 0; mc < LL; mc += 64) {
    __syncthreads();
    #pragma unroll
    for (int it = 0; it < 2; ++it) {
      int si = t + it * 256, r = si >> 3, c8 = (si & 7) * 8;
      *(bf16x8*)&ks[r * 72 + c8] =
          *(const bf16x8*)(kc + ((size_t)(b * LL + mc + r)) * DD + h * HDD + c8);
      *(bf16x8*)&vs[r * 72 + c8] =
          *(const bf16x8*)(vt + ((size_t)((b * HH + h) * HDD + r)) * LL + mc + c8);
    }
    __syncthreads();
    #pragma unroll
    for (int j = 0; j < 4; ++j) {
      bf16x8 b0 = *(const bf16x8*)&ks[(j * 16 + fr) * 72 + fq * 8];
      bf16x8 b1 = *(const bf16x8*)&ks[(j * 16 + fr) * 72 + 32 + fq * 8];
      f32x4 sAcc = (f32x4){0.f, 0.f, 0.f, 0.f};
      sAcc = __builtin_amdgcn_mfma_f32_16x16x32_bf16(qa0, b0, sAcc, 0, 0, 0);
      sAcc = __builtin_amdgcn_mfma_f32_16x16x32_bf16(qa1, b1, sAcc, 0, 0, 0);
      #pragma unroll
      for (int rg = 0; rg < 4; ++rg) {
        float p = expf(sAcc[rg] * sfac - rm[rg]) * rzi[rg];
        float q = fminf(fmaxf(rintf(p * ipscale), 0.0f), 255.0f);
        ps[wave][(fq * 4 + rg) * 72 + j * 16 + fr] = f2bf(q);
      }
    }
    __syncthreads();
    bf16x8 pa0 = *(const bf16x8*)&ps[wave][fr * 72 + fq * 8];
    bf16x8 pa1 = *(const bf16x8*)&ps[wave][fr * 72 + 32 + fq * 8];
    #pragma unroll
    for (int jd = 0; jd < 4; ++jd) {
      bf16x8 vb0 = *(const bf16x8*)&vs[(jd * 16 + fr) * 72 + fq * 8];
      bf16x8 vb1 = *(const bf16x8*)&vs[(jd * 16 + fr) * 72 + 32 + fq * 8];
      acc[jd] = __builtin_amdgcn_mfma_f32_16x16x32_bf16(pa0, vb0, acc[jd], 0, 0, 0);
      acc[jd] = __builtin_amdgcn_mfma_f32_16x16x32_bf16(pa1, vb1, acc[jd], 0, 0, 0);
    }
  }
  const float osc = pscale * sv2;
  #pragma unroll
  for (int jd = 0; jd < 4; ++jd)
    #pragma unroll
    for (int rg = 0; rg < 4; ++rg) {
      int row = l0 + wave * 16 + fq * 4 + rg;
      ctx[((size_t)(b * LL + row)) * DD + h * HDD + jd * 16 + fr] = acc[jd][rg] * osc;
    }
}

extern "C" void kernel_launch(void* const* d_in, const int* in_sizes, int n_in,
                              void* d_out, int out_size, void* d_ws, size_t ws_size,
                              hipStream_t stream) {
  const float* x    = (const float*)d_in[0];
  const float* ln1g = (const float*)d_in[1];
  const float* ln1b = (const float*)d_in[2];
  const float* wq   = (const float*)d_in[3];
  const float* bq   = (const float*)d_in[4];
  const float* wk   = (const float*)d_in[5];
  const float* bk   = (const float*)d_in[6];
  const float* wv   = (const float*)d_in[7];
  const float* bv   = (const float*)d_in[8];
  const float* wo   = (const float*)d_in[9];
  const float* bo   = (const float*)d_in[10];
  const float* ln2g = (const float*)d_in[11];
  const float* ln2b = (const float*)d_in[12];
  const float* wfc  = (const float*)d_in[13];
  const float* bfc  = (const float*)d_in[14];
  const float* wpj  = (const float*)d_in[15];
  const float* bpj  = (const float*)d_in[16];
  float* out = (float*)d_out;
  float* ws = (float*)d_ws;

  size_t off = 0;
  float* scal = ws + off; off += 256;
  unsigned short* wqQ  = (unsigned short*)(ws + off); off += (size_t)DD*DD/2;
  unsigned short* wkQ  = (unsigned short*)(ws + off); off += (size_t)DD*DD/2;
  unsigned short* wvQ  = (unsigned short*)(ws + off); off += (size_t)DD*DD/2;
  unsigned short* woQ  = (unsigned short*)(ws + off); off += (size_t)DD*DD/2;
  unsigned short* wfcQ = (unsigned short*)(ws + off); off += (size_t)FFD*DD/2;
  unsigned short* wpjQ = (unsigned short*)(ws + off); off += (size_t)DD*FFD/2;
  float* hbuf = ws + off; off += (size_t)MTOK*DD;   // h, later o_lin
  float* qb   = ws + off; off += (size_t)MTOK*DD;   // q raw, later h2
  float* kb   = ws + off; off += (size_t)MTOK*DD;
  float* vb   = ws + off; off += (size_t)MTOK*DD;   // v raw, later proj_lin
  float* rowm = ws + off; off += (size_t)BB*HH*LL;
  float* rowz = ws + off; off += (size_t)BB*HH*LL;
  float* ctxb = ws + off; off += (size_t)MTOK*DD;
  float* x1   = ws + off; off += (size_t)MTOK*DD;
  float* fcb  = ws + off; off += (size_t)MTOK*FFD;
  unsigned short* qcod = (unsigned short*)(ws + off); off += (size_t)MTOK*DD/2;
  unsigned short* kcod = (unsigned short*)(ws + off); off += (size_t)MTOK*DD/2;
  unsigned short* vtc  = (unsigned short*)(ws + off); off += (size_t)MTOK*DD/2;

  const int ND  = MTOK*DD/4;
  const int NF  = MTOK*FFD/4;
  const int NW  = DD*DD/4;
  const int NWF = DD*FFD/4;

  auto g4 = [](int n4){ int g = (n4 + 255) / 256; return g > 4096 ? 4096 : g; };

  k_init<<<1, 64, 0, stream>>>(scal);

  k_absmax<<<1024, 256, 0, stream>>>(wq,  NW,  scal+0);
  k_absmax<<<1024, 256, 0, stream>>>(wk,  NW,  scal+1);
  k_absmax<<<1024, 256, 0, stream>>>(wv,  NW,  scal+2);
  k_absmax<<<1024, 256, 0, stream>>>(wo,  NW,  scal+3);
  k_absmax<<<2048, 256, 0, stream>>>(wfc, NWF, scal+4);
  k_absmax<<<2048, 256, 0, stream>>>(wpj, NWF, scal+5);

  k_quantw_bf<<<g4(NW),  256, 0, stream>>>(wq,  wqQ,  NW,  scal+0);
  k_quantw_bf<<<g4(NW),  256, 0, stream>>>(wk,  wkQ,  NW,  scal+1);
  k_quantw_bf<<<g4(NW),  256, 0, stream>>>(wv,  wvQ,  NW,  scal+2);
  k_quantw_bf<<<g4(NW),  256, 0, stream>>>(wo,  woQ,  NW,  scal+3);
  k_quantw_bf<<<g4(NWF), 256, 0, stream>>>(wfc, wfcQ, NWF, scal+4);
  k_quantw_bf<<<g4(NWF), 256, 0, stream>>>(wpj, wpjQ, NWF, scal+5);

  k_ln<<<MTOK, 256, 0, stream>>>(x, ln1g, ln1b, hbuf);

  k_gemm_mfma<<<dim3(8, 32), 256, 0, stream>>>(hbuf, wqQ, bq, scal+0, qb, DD, DD, scal+6,  scal+7);
  k_gemm_mfma<<<dim3(8, 32), 256, 0, stream>>>(hbuf, wkQ, bk, scal+1, kb, DD, DD, scal+8,  scal+9);
  k_gemm_mfma<<<dim3(8, 32), 256, 0, stream>>>(hbuf, wvQ, bv, scal+2, vb, DD, DD, scal+10, scal+11);

  k_quant_codes<<<g4(ND), 256, 0, stream>>>(qb, qcod, ND, scal+6);
  k_quant_codes<<<g4(ND), 256, 0, stream>>>(kb, kcod, ND, scal+8);
  k_quant_codes_vt<<<dim3(8, 16, 8), 256, 0, stream>>>(vb, vtc, scal+10);

  k_attn_a_mfma<<<dim3(8, 16, 8), 256, 0, stream>>>(qcod, kcod, scal+6, scal+8,
                                                    rowm, rowz, scal+18);
  k_attn_b_mfma<<<dim3(8, 16, 8), 256, 0, stream>>>(qcod, kcod, vtc, scal+6, scal+8, scal+10,
                                                    rowm, rowz, scal+18, ctxb);

  k_gemm_mfma<<<dim3(8, 32), 256, 0, stream>>>(ctxb, woQ, bo, scal+3, hbuf, DD, DD, scal+19, scal+20);
  k_quant_res<<<g4(ND), 256, 0, stream>>>(hbuf, x, x1, ND, scal+19, scal+20);

  k_ln<<<MTOK, 256, 0, stream>>>(x1, ln2g, ln2b, qb);
  k_gemm_mfma<<<dim3(32, 32), 256, 0, stream>>>(qb, wfcQ, bfc, scal+4, fcb, FFD, DD, scal+21, scal+22);
  k_quant_gelu<<<g4(NF), 256, 0, stream>>>(fcb, NF, scal+21, scal+22);

  k_gemm_mfma<<<dim3(8, 32), 256, 0, stream>>>(fcb, wpjQ, bpj, scal+5, vb, DD, FFD, scal+23, scal+24);
  k_quant_res<<<g4(ND), 256, 0, stream>>>(vb, x1, out, ND, scal+23, scal+24);
}

// Round 4
// 798.396 us; speedup vs baseline: 3.5312x; 1.0922x over previous
//
#include <hip/hip_runtime.h>
#include <cmath>

#define BB 8
#define LL 512
#define DD 1024
#define HH 16
#define HDD 64
#define FFD 4096
#define MTOK (BB*LL)
#define EPSF 1e-5f
#define BK 32

typedef __attribute__((ext_vector_type(8))) short bf16x8;
typedef __attribute__((ext_vector_type(4))) float f32x4;

// scal slots: 0..5 weight absmax (q,k,v,o,fc,pj)
// 6,7 q obs | 8,9 k | 10,11 v | 18 maxp | 19,20 o | 21,22 fc | 23,24 pj

__device__ inline void atomicMaxPos(float* addr, float v) {
  atomicMax((unsigned int*)addr, __float_as_uint(v));  // v >= 0, slot init 0
}

__device__ inline unsigned short f2bf(float x) {  // RNE to bf16 bits
  unsigned int u = __float_as_uint(x);
  u += 0x7fffu + ((u >> 16) & 1u);
  return (unsigned short)(u >> 16);
}
__device__ inline float bf2f(unsigned short h) {
  return __uint_as_float((unsigned int)h << 16);
}

__global__ void k_init(float* __restrict__ s) { s[threadIdx.x] = 0.0f; }

__global__ void k_bcat(const float* __restrict__ b0, const float* __restrict__ b1,
                       const float* __restrict__ b2, float* __restrict__ dst) {
  int i = blockIdx.x * blockDim.x + threadIdx.x;
  if (i < 3072) dst[i] = i < 1024 ? b0[i] : (i < 2048 ? b1[i - 1024] : b2[i - 2048]);
}

__global__ void k_absmax(const float* __restrict__ w, int n4, float* __restrict__ slot) {
  const float4* w4 = (const float4*)w;
  float m = 0.0f;
  for (int i = blockIdx.x * blockDim.x + threadIdx.x; i < n4; i += gridDim.x * blockDim.x) {
    float4 v = w4[i];
    m = fmaxf(m, fmaxf(fmaxf(fabsf(v.x), fabsf(v.y)), fmaxf(fabsf(v.z), fabsf(v.w))));
  }
  #pragma unroll
  for (int o = 32; o; o >>= 1) m = fmaxf(m, __shfl_down(m, o, 64));
  __shared__ float sb[4];
  int lane = threadIdx.x & 63, wid = threadIdx.x >> 6;
  if (lane == 0) sb[wid] = m;
  __syncthreads();
  if (threadIdx.x == 0) atomicMaxPos(slot, fmaxf(fmaxf(sb[0], sb[1]), fmaxf(sb[2], sb[3])));
}

__global__ void k_quantw_bf(const float* __restrict__ w, unsigned short* __restrict__ wq, int n4,
                            const float* __restrict__ slot) {
  float s = fmaxf(*slot / 127.0f, 1e-8f);
  const float4* w4 = (const float4*)w;
  ushort4* q4 = (ushort4*)wq;
  for (int i = blockIdx.x * blockDim.x + threadIdx.x; i < n4; i += gridDim.x * blockDim.x) {
    float4 v = w4[i];
    ushort4 o;
    o.x = f2bf(fminf(fmaxf(rintf(v.x / s), -128.0f), 127.0f));
    o.y = f2bf(fminf(fmaxf(rintf(v.y / s), -128.0f), 127.0f));
    o.z = f2bf(fminf(fmaxf(rintf(v.z / s), -128.0f), 127.0f));
    o.w = f2bf(fminf(fmaxf(rintf(v.w / s), -128.0f), 127.0f));
    q4[i] = o;
  }
}

__device__ inline float2 fq_params(const float* sHi, const float* sNeg) {
  float hi = *sHi, lo = -(*sNeg);
  float scale = fmaxf((hi - lo) / 255.0f, 1e-8f);
  float zp = rintf(-lo / scale);
  return make_float2(scale, zp);
}
__device__ inline float fq1(float x, float scale, float zp) {
  float q = fminf(fmaxf(rintf(x / scale) + zp, 0.0f), 255.0f);
  return (q - zp) * scale;
}
__device__ inline float2 fq_params2(const float* sHi, const float* sNeg) {
  float2 p1 = fq_params(sHi, sNeg);
  float hi2 = fq1(*sHi, p1.x, p1.y);
  float lo2 = fq1(-(*sNeg), p1.x, p1.y);
  float scale = fmaxf((hi2 - lo2) / 255.0f, 1e-8f);
  float zp = rintf(-lo2 / scale);
  return make_float2(scale, zp);
}
__device__ inline float code2(float x, float2 p1, float2 p2) {
  float v1 = fq1(x, p1.x, p1.y);
  float q = fminf(fmaxf(rintf(v1 / p2.x) + p2.y, 0.0f), 255.0f);
  return q - p2.y;
}

// raw qkv (ld 3072) -> double-fq -> bf16 integer codes packed [4096][1024]
__global__ void k_quant_codes(const float* __restrict__ src, int colBase,
                              unsigned short* __restrict__ oc, const float* __restrict__ sl) {
  float2 p1 = fq_params(sl, sl + 1);
  float2 p2 = fq_params2(sl, sl + 1);
  const int n4 = MTOK * DD / 4;
  for (int i = blockIdx.x * blockDim.x + threadIdx.x; i < n4; i += gridDim.x * blockDim.x) {
    int row = i >> 8, c = (i & 255) * 4;
    float4 v = *(const float4*)(src + (size_t)row * 3072 + colBase + c);
    ushort4 o;
    o.x = f2bf(code2(v.x, p1, p2)); o.y = f2bf(code2(v.y, p1, p2));
    o.z = f2bf(code2(v.z, p1, p2)); o.w = f2bf(code2(v.w, p1, p2));
    *(ushort4*)&oc[(size_t)row * DD + c] = o;
  }
}

// V codes per-head transposed: vt[((b*H+h)*64+d)*512 + m]; src ld 3072, col base 2048
__global__ __launch_bounds__(256) void k_quant_codes_vt(
    const float* __restrict__ src, unsigned short* __restrict__ vt,
    const float* __restrict__ sl) {
  __shared__ unsigned short tile[64 * 68];
  float2 p1 = fq_params(sl, sl + 1);
  float2 p2 = fq_params2(sl, sl + 1);
  const int m0 = blockIdx.x * 64, h = blockIdx.y, b = blockIdx.z;
  const int t = threadIdx.x;
  const int r = t >> 2, c0 = (t & 3) * 16;
  const float* s4 = src + ((size_t)(b * LL + m0 + r)) * 3072 + 2048 + h * HDD + c0;
  #pragma unroll
  for (int i = 0; i < 4; ++i) {
    float4 v = *(const float4*)(s4 + i * 4);
    ushort4 o;
    o.x = f2bf(code2(v.x, p1, p2)); o.y = f2bf(code2(v.y, p1, p2));
    o.z = f2bf(code2(v.z, p1, p2)); o.w = f2bf(code2(v.w, p1, p2));
    *(ushort4*)&tile[r * 68 + c0 + i * 4] = o;
  }
  __syncthreads();
  const int dr = t >> 2, ms = (t & 3) * 16;
  unsigned short* dst = vt + ((size_t)((b * HH + h) * HDD + dr)) * LL + m0 + ms;
  #pragma unroll
  for (int i = 0; i < 4; ++i) {
    ushort4 o;
    o.x = tile[(ms + i * 4 + 0) * 68 + dr];
    o.y = tile[(ms + i * 4 + 1) * 68 + dr];
    o.z = tile[(ms + i * 4 + 2) * 68 + dr];
    o.w = tile[(ms + i * 4 + 3) * 68 + dr];
    *(ushort4*)(dst + i * 4) = o;
  }
}

// lin = p0+p1+bias -> minmax observer
__global__ void k_sum_minmax(const float* __restrict__ p0, const float* __restrict__ p1,
                             const float* __restrict__ bias, int n4, int cmask,
                             float* __restrict__ sl) {
  float hi = 0.0f, ng = 0.0f;
  for (int i = blockIdx.x * blockDim.x + threadIdx.x; i < n4; i += gridDim.x * blockDim.x) {
    float4 a = ((const float4*)p0)[i];
    float4 b = ((const float4*)p1)[i];
    float4 bc = *(const float4*)(bias + (i & cmask) * 4);
    float vx = a.x + b.x + bc.x, vy = a.y + b.y + bc.y;
    float vz = a.z + b.z + bc.z, vw = a.w + b.w + bc.w;
    hi = fmaxf(hi, fmaxf(fmaxf(vx, vy), fmaxf(vz, vw)));
    ng = fmaxf(ng, fmaxf(fmaxf(-vx, -vy), fmaxf(-vz, -vw)));
  }
  #pragma unroll
  for (int o = 32; o; o >>= 1) {
    hi = fmaxf(hi, __shfl_down(hi, o, 64));
    ng = fmaxf(ng, __shfl_down(ng, o, 64));
  }
  __shared__ float sh[4], sn[4];
  int lane = threadIdx.x & 63, wid = threadIdx.x >> 6;
  if (lane == 0) { sh[wid] = hi; sn[wid] = ng; }
  __syncthreads();
  if (threadIdx.x == 0) {
    atomicMaxPos(sl, fmaxf(fmaxf(sh[0], sh[1]), fmaxf(sh[2], sh[3])));
    atomicMaxPos(sl + 1, fmaxf(fmaxf(sn[0], sn[1]), fmaxf(sn[2], sn[3])));
  }
}

// out = res + fq(p0+p1+bias)
__global__ void k_quant_res2(const float* __restrict__ p0, const float* __restrict__ p1,
                             const float* __restrict__ bias, const float* __restrict__ res,
                             float* __restrict__ out, int n4, int cmask,
                             const float* __restrict__ sl) {
  float2 p = fq_params(sl, sl + 1);
  for (int i = blockIdx.x * blockDim.x + threadIdx.x; i < n4; i += gridDim.x * blockDim.x) {
    float4 a = ((const float4*)p0)[i];
    float4 b = ((const float4*)p1)[i];
    float4 bc = *(const float4*)(bias + (i & cmask) * 4);
    float4 r = ((const float4*)res)[i];
    float4 o;
    o.x = r.x + fq1(a.x + b.x + bc.x, p.x, p.y);
    o.y = r.y + fq1(a.y + b.y + bc.y, p.x, p.y);
    o.z = r.z + fq1(a.z + b.z + bc.z, p.x, p.y);
    o.w = r.w + fq1(a.w + b.w + bc.w, p.x, p.y);
    ((float4*)out)[i] = o;
  }
}

__device__ inline float gelu_exact(float g) {
  return 0.5f * g * (1.0f + erff(g * 0.7071067811865475f));
}

// fc raw -> gelu(fq(.)) -> bf16 hi/lo
__global__ void k_gelu_codes(const float* __restrict__ x,
                             unsigned short* __restrict__ ghi, unsigned short* __restrict__ glo,
                             int n4, const float* __restrict__ sl) {
  float2 p = fq_params(sl, sl + 1);
  for (int i = blockIdx.x * blockDim.x + threadIdx.x; i < n4; i += gridDim.x * blockDim.x) {
    float4 v = ((const float4*)x)[i];
    float g0 = gelu_exact(fq1(v.x, p.x, p.y)), g1 = gelu_exact(fq1(v.y, p.x, p.y));
    float g2 = gelu_exact(fq1(v.z, p.x, p.y)), g3 = gelu_exact(fq1(v.w, p.x, p.y));
    ushort4 h, l;
    h.x = f2bf(g0); l.x = f2bf(g0 - bf2f(h.x));
    h.y = f2bf(g1); l.y = f2bf(g1 - bf2f(h.y));
    h.z = f2bf(g2); l.z = f2bf(g2 - bf2f(h.z));
    h.w = f2bf(g3); l.w = f2bf(g3 - bf2f(h.w));
    ((ushort4*)ghi)[i] = h;
    ((ushort4*)glo)[i] = l;
  }
}

__device__ inline float block_sum256(float v, float* sb) {
  #pragma unroll
  for (int o = 32; o; o >>= 1) v += __shfl_down(v, o, 64);
  int lane = threadIdx.x & 63, wid = threadIdx.x >> 6;
  __syncthreads();
  if (lane == 0) sb[wid] = v;
  __syncthreads();
  return sb[0] + sb[1] + sb[2] + sb[3];
}

// LayerNorm -> bf16 hi/lo pair
__global__ __launch_bounds__(256) void k_ln_bf(const float* __restrict__ x, const float* __restrict__ g,
                                               const float* __restrict__ bta,
                                               unsigned short* __restrict__ ohi,
                                               unsigned short* __restrict__ olo) {
  __shared__ float sb[4];
  int row = blockIdx.x;
  const float4* xr = (const float4*)(x + (size_t)row * DD);
  float4 v = xr[threadIdx.x];
  float mu = block_sum256(v.x + v.y + v.z + v.w, sb) * (1.0f / DD);
  float dx = v.x - mu, dy = v.y - mu, dz = v.z - mu, dw = v.w - mu;
  float var = block_sum256(dx*dx + dy*dy + dz*dz + dw*dw, sb) * (1.0f / DD);
  float rs = 1.0f / sqrtf(var + EPSF);
  float4 gv = ((const float4*)g)[threadIdx.x];
  float4 bv = ((const float4*)bta)[threadIdx.x];
  float o0 = dx * rs * gv.x + bv.x;
  float o1 = dy * rs * gv.y + bv.y;
  float o2 = dz * rs * gv.z + bv.z;
  float o3 = dw * rs * gv.w + bv.w;
  ushort4 h, l;
  h.x = f2bf(o0); l.x = f2bf(o0 - bf2f(h.x));
  h.y = f2bf(o1); l.y = f2bf(o1 - bf2f(h.y));
  h.z = f2bf(o2); l.z = f2bf(o2 - bf2f(h.z));
  h.w = f2bf(o3); l.w = f2bf(o3 - bf2f(h.w));
  ((ushort4*)(ohi + (size_t)row * DD))[threadIdx.x] = h;
  ((ushort4*)(olo + (size_t)row * DD))[threadIdx.x] = l;
}

// MFMA GEMM on pre-split bf16 A (hi/lo) and bf16 weight codes.
// C[row0..+128, col0..+128] (+bias, +observer if obs). Optional split-K via blockIdx.z.
__global__ __launch_bounds__(256, 3) void k_gemm_bf(
    const unsigned short* __restrict__ Ahi, const unsigned short* __restrict__ Alo,
    const unsigned short* __restrict__ Bq,
    const float* __restrict__ bias, const float* __restrict__ wsc, float* __restrict__ obs,
    float* __restrict__ C, int ldC, int K, int kLen, int segShift, size_t partStride) {
  __shared__ unsigned short sAh[128 * BK];
  __shared__ unsigned short sAl[128 * BK];
  __shared__ unsigned short sB [128 * BK];
  __shared__ float redH, redN;
  const int t = threadIdx.x;
  const int col0 = blockIdx.x * 128, row0 = blockIdx.y * 128;
  const int kOff = blockIdx.z * kLen;
  float* Cp = C + (size_t)blockIdx.z * partStride;
  const int wave = t >> 6, lane = t & 63;
  const int wr = (wave >> 1) * 64, wc = (wave & 1) * 64;
  const int fr = lane & 15, fq = lane >> 4;
  const int seg = col0 >> segShift;
  const float s = fmaxf(wsc[seg] / 127.0f, 1e-8f);
  if (t == 0) { redH = 0.f; redN = 0.f; }

  f32x4 acc[4][4];
  #pragma unroll
  for (int i = 0; i < 4; ++i)
    #pragma unroll
    for (int j = 0; j < 4; ++j) acc[i][j] = (f32x4){0.f, 0.f, 0.f, 0.f};

  const int srow = t >> 2, skc = (t & 3) * 8;
  for (int k0 = kOff; k0 < kOff + kLen; k0 += BK) {
    __syncthreads();
    #pragma unroll
    for (int it = 0; it < 2; ++it) {
      int r = srow + it * 64;
      size_t ga = (size_t)(row0 + r) * K + k0 + skc;
      size_t gb = (size_t)(col0 + r) * K + k0 + skc;
      *(bf16x8*)&sAh[r * BK + skc] = *(const bf16x8*)(Ahi + ga);
      *(bf16x8*)&sAl[r * BK + skc] = *(const bf16x8*)(Alo + ga);
      *(bf16x8*)&sB [r * BK + skc] = *(const bf16x8*)(Bq + gb);
    }
    __syncthreads();
    bf16x8 ah[4], al[4], bb[4];
    #pragma unroll
    for (int i = 0; i < 4; ++i) {
      ah[i] = *(const bf16x8*)&sAh[(wr + i * 16 + fr) * BK + fq * 8];
      al[i] = *(const bf16x8*)&sAl[(wr + i * 16 + fr) * BK + fq * 8];
      bb[i] = *(const bf16x8*)&sB [(wc + i * 16 + fr) * BK + fq * 8];
    }
    #pragma unroll
    for (int i = 0; i < 4; ++i)
      #pragma unroll
      for (int j = 0; j < 4; ++j) {
        acc[i][j] = __builtin_amdgcn_mfma_f32_16x16x32_bf16(ah[i], bb[j], acc[i][j], 0, 0, 0);
        acc[i][j] = __builtin_amdgcn_mfma_f32_16x16x32_bf16(al[i], bb[j], acc[i][j], 0, 0, 0);
      }
  }

  float ohi = 0.f, ong = 0.f;
  #pragma unroll
  for (int i = 0; i < 4; ++i) {
    #pragma unroll
    for (int j = 0; j < 4; ++j) {
      int col = col0 + wc + j * 16 + fr;
      float bcol = bias ? bias[col] : 0.0f;
      #pragma unroll
      for (int rg = 0; rg < 4; ++rg) {
        int row = row0 + wr + i * 16 + fq * 4 + rg;
        float val = acc[i][j][rg] * s + bcol;
        if (obs) { ohi = fmaxf(ohi, val); ong = fmaxf(ong, -val); }
        Cp[(size_t)row * ldC + col] = val;
      }
    }
  }
  if (obs) {
    #pragma unroll
    for (int o = 32; o; o >>= 1) {
      ohi = fmaxf(ohi, __shfl_down(ohi, o, 64));
      ong = fmaxf(ong, __shfl_down(ong, o, 64));
    }
    if (lane == 0) { atomicMaxPos(&redH, ohi); atomicMaxPos(&redN, ong); }
    __syncthreads();
    if (t == 0) {
      atomicMaxPos(obs + 2 * seg, redH);
      atomicMaxPos(obs + 2 * seg + 1, redN);
    }
  }
}

// ---- MFMA attention on integer bf16 codes ----
__global__ __launch_bounds__(256) void k_attn_a_mfma(
    const unsigned short* __restrict__ qc, const unsigned short* __restrict__ kc,
    const float* __restrict__ slq, const float* __restrict__ slk,
    float* __restrict__ rowm, float* __restrict__ rowz, float* __restrict__ maxp) {
  __shared__ unsigned short ks[64 * 72];
  __shared__ float redp;
  const int t = threadIdx.x, wave = t >> 6, lane = t & 63;
  const int fr = lane & 15, fq = lane >> 4;
  const int l0 = blockIdx.x * 64, h = blockIdx.y, b = blockIdx.z;
  const float sfac = fq_params2(slq, slq + 1).x * fq_params2(slk, slk + 1).x * 0.125f;
  if (t == 0) redp = 0.f;
  const unsigned short* qrow = qc + ((size_t)(b * LL + l0 + wave * 16 + fr)) * DD + h * HDD;
  bf16x8 qa0 = *(const bf16x8*)(qrow + fq * 8);
  bf16x8 qa1 = *(const bf16x8*)(qrow + 32 + fq * 8);
  float mrun[4] = {-INFINITY, -INFINITY, -INFINITY, -INFINITY};
  float zrun[4] = {0.f, 0.f, 0.f, 0.f};
  for (int mc = 0; mc < LL; mc += 64) {
    __syncthreads();
    #pragma unroll
    for (int it = 0; it < 2; ++it) {
      int si = t + it * 256, r = si >> 3, c8 = (si & 7) * 8;
      *(bf16x8*)&ks[r * 72 + c8] =
          *(const bf16x8*)(kc + ((size_t)(b * LL + mc + r)) * DD + h * HDD + c8);
    }
    __syncthreads();
    float sv[4][4];
    #pragma unroll
    for (int j = 0; j < 4; ++j) {
      bf16x8 b0 = *(const bf16x8*)&ks[(j * 16 + fr) * 72 + fq * 8];
      bf16x8 b1 = *(const bf16x8*)&ks[(j * 16 + fr) * 72 + 32 + fq * 8];
      f32x4 sAcc = (f32x4){0.f, 0.f, 0.f, 0.f};
      sAcc = __builtin_amdgcn_mfma_f32_16x16x32_bf16(qa0, b0, sAcc, 0, 0, 0);
      sAcc = __builtin_amdgcn_mfma_f32_16x16x32_bf16(qa1, b1, sAcc, 0, 0, 0);
      #pragma unroll
      for (int rg = 0; rg < 4; ++rg) sv[j][rg] = sAcc[rg] * sfac;
    }
    #pragma unroll
    for (int rg = 0; rg < 4; ++rg) {
      float nm = mrun[rg];
      #pragma unroll
      for (int j = 0; j < 4; ++j) nm = fmaxf(nm, sv[j][rg]);
      float z = zrun[rg] * expf(mrun[rg] - nm);
      #pragma unroll
      for (int j = 0; j < 4; ++j) z += expf(sv[j][rg] - nm);
      zrun[rg] = z; mrun[rg] = nm;
    }
  }
  #pragma unroll
  for (int off = 1; off < 16; off <<= 1) {
    #pragma unroll
    for (int rg = 0; rg < 4; ++rg) {
      float om = __shfl_xor(mrun[rg], off, 64);
      float oz = __shfl_xor(zrun[rg], off, 64);
      float nm = fmaxf(mrun[rg], om);
      zrun[rg] = zrun[rg] * expf(mrun[rg] - nm) + oz * expf(om - nm);
      mrun[rg] = nm;
    }
  }
  if (fr == 0) {
    int rid = (b * HH + h) * LL + l0 + wave * 16 + fq * 4;
    float lmax = 0.f;
    #pragma unroll
    for (int rg = 0; rg < 4; ++rg) {
      rowm[rid + rg] = mrun[rg]; rowz[rid + rg] = zrun[rg];
      lmax = fmaxf(lmax, 1.0f / zrun[rg]);
    }
    atomicMaxPos(&redp, lmax);
  }
  __syncthreads();
  if (t == 0) atomicMaxPos(maxp, redp);
}

__global__ __launch_bounds__(256) void k_attn_b_mfma(
    const unsigned short* __restrict__ qc, const unsigned short* __restrict__ kc,
    const unsigned short* __restrict__ vt,
    const float* __restrict__ slq, const float* __restrict__ slk, const float* __restrict__ slv,
    const float* __restrict__ rowm, const float* __restrict__ rowz,
    const float* __restrict__ maxp,
    unsigned short* __restrict__ chi, unsigned short* __restrict__ clo) {
  __shared__ unsigned short ks[64 * 72];
  __shared__ unsigned short vs[64 * 72];
  __shared__ unsigned short ps[4][16 * 72];
  const int t = threadIdx.x, wave = t >> 6, lane = t & 63;
  const int fr = lane & 15, fq = lane >> 4;
  const int l0 = blockIdx.x * 64, h = blockIdx.y, b = blockIdx.z;
  const float sfac = fq_params2(slq, slq + 1).x * fq_params2(slk, slk + 1).x * 0.125f;
  const float sv2 = fq_params2(slv, slv + 1).x;
  const float pscale = fmaxf(maxp[0] / 255.0f, 1e-8f);
  const float ipscale = 1.0f / pscale;
  const int ridb = (b * HH + h) * LL + l0 + wave * 16 + fq * 4;
  float rm[4], rzi[4];
  #pragma unroll
  for (int rg = 0; rg < 4; ++rg) { rm[rg] = rowm[ridb + rg]; rzi[rg] = 1.0f / rowz[ridb + rg]; }
  const unsigned short* qrow = qc + ((size_t)(b * LL + l0 + wave * 16 + fr)) * DD + h * HDD;
  bf16x8 qa0 = *(const bf16x8*)(qrow + fq * 8);
  bf16x8 qa1 = *(const bf16x8*)(qrow + 32 + fq * 8);
  f32x4 acc[4];
  #pragma unroll
  for (int jd = 0; jd < 4; ++jd) acc[jd] = (f32x4){0.f, 0.f, 0.f, 0.f};

  for (int mc = 0; mc < LL; mc += 64) {
    __syncthreads();
    #pragma unroll
    for (int it = 0; it < 2; ++it) {
      int si = t + it * 256, r = si >> 3, c8 = (si & 7) * 8;
      *(bf16x8*)&ks[r * 72 + c8] =
          *(const bf16x8*)(kc + ((size_t)(b * LL + mc + r)) * DD + h * HDD + c8);
      *(bf16x8*)&vs[r * 72 + c8] =
          *(const bf16x8*)(vt + ((size_t)((b * HH + h) * HDD + r)) * LL + mc + c8);
    }
    __syncthreads();
    #pragma unroll
    for (int j = 0; j < 4; ++j) {
      bf16x8 b0 = *(const bf16x8*)&ks[(j * 16 + fr) * 72 + fq * 8];
      bf16x8 b1 = *(const bf16x8*)&ks[(j * 16 + fr) * 72 + 32 + fq * 8];
      f32x4 sAcc = (f32x4){0.f, 0.f, 0.f, 0.f};
      sAcc = __builtin_amdgcn_mfma_f32_16x16x32_bf16(qa0, b0, sAcc, 0, 0, 0);
      sAcc = __builtin_amdgcn_mfma_f32_16x16x32_bf16(qa1, b1, sAcc, 0, 0, 0);
      #pragma unroll
      for (int rg = 0; rg < 4; ++rg) {
        float p = expf(sAcc[rg] * sfac - rm[rg]) * rzi[rg];
        float q = fminf(fmaxf(rintf(p * ipscale), 0.0f), 255.0f);
        ps[wave][(fq * 4 + rg) * 72 + j * 16 + fr] = f2bf(q);
      }
    }
    __syncthreads();
    bf16x8 pa0 = *(const bf16x8*)&ps[wave][fr * 72 + fq * 8];
    bf16x8 pa1 = *(const bf16x8*)&ps[wave][fr * 72 + 32 + fq * 8];
    #pragma unroll
    for (int jd = 0; jd < 4; ++jd) {
      bf16x8 vb0 = *(const bf16x8*)&vs[(jd * 16 + fr) * 72 + fq * 8];
      bf16x8 vb1 = *(const bf16x8*)&vs[(jd * 16 + fr) * 72 + 32 + fq * 8];
      acc[jd] = __builtin_amdgcn_mfma_f32_16x16x32_bf16(pa0, vb0, acc[jd], 0, 0, 0);
      acc[jd] = __builtin_amdgcn_mfma_f32_16x16x32_bf16(pa1, vb1, acc[jd], 0, 0, 0);
    }
  }
  const float osc = pscale * sv2;
  #pragma unroll
  for (int jd = 0; jd < 4; ++jd)
    #pragma unroll
    for (int rg = 0; rg < 4; ++rg) {
      int row = l0 + wave * 16 + fq * 4 + rg;
      size_t cidx = ((size_t)(b * LL + row)) * DD + h * HDD + jd * 16 + fr;
      float val = acc[jd][rg] * osc;
      unsigned short hh = f2bf(val);
      chi[cidx] = hh;
      clo[cidx] = f2bf(val - bf2f(hh));
    }
}

extern "C" void kernel_launch(void* const* d_in, const int* in_sizes, int n_in,
                              void* d_out, int out_size, void* d_ws, size_t ws_size,
                              hipStream_t stream) {
  const float* x    = (const float*)d_in[0];
  const float* ln1g = (const float*)d_in[1];
  const float* ln1b = (const float*)d_in[2];
  const float* wq   = (const float*)d_in[3];
  const float* bq   = (const float*)d_in[4];
  const float* wk   = (const float*)d_in[5];
  const float* bk   = (const float*)d_in[6];
  const float* wv   = (const float*)d_in[7];
  const float* bv   = (const float*)d_in[8];
  const float* wo   = (const float*)d_in[9];
  const float* bo   = (const float*)d_in[10];
  const float* ln2g = (const float*)d_in[11];
  const float* ln2b = (const float*)d_in[12];
  const float* wfc  = (const float*)d_in[13];
  const float* bfc  = (const float*)d_in[14];
  const float* wpj  = (const float*)d_in[15];
  const float* bpj  = (const float*)d_in[16];
  float* out = (float*)d_out;
  float* ws = (float*)d_ws;

  size_t off = 0;
  float* scal = ws + off; off += 256;
  float* bcat = ws + off; off += 3072;
  unsigned short* wcatQ = (unsigned short*)(ws + off); off += (size_t)3072*DD/2;   // q,k,v stacked
  unsigned short* woQ   = (unsigned short*)(ws + off); off += (size_t)DD*DD/2;
  unsigned short* wfcQ  = (unsigned short*)(ws + off); off += (size_t)FFD*DD/2;
  unsigned short* wpjQ  = (unsigned short*)(ws + off); off += (size_t)DD*FFD/2;
  unsigned short* abhi  = (unsigned short*)(ws + off); off += (size_t)MTOK*DD/2;   // h1 -> ctx -> h2
  unsigned short* ablo  = (unsigned short*)(ws + off); off += (size_t)MTOK*DD/2;
  float* qkvb = ws + off; off += (size_t)MTOK*3072;   // raw qkv; later opart[2]; later gelhi
  float* x1rg = ws + off; off += (size_t)MTOK*DD;     // first qcod+kcod; later x1
  unsigned short* vtc = (unsigned short*)(ws + off); off += (size_t)MTOK*DD/2;
  float* rowm = ws + off; off += (size_t)BB*HH*LL;
  float* rowz = ws + off; off += (size_t)BB*HH*LL;
  float* fcb  = ws + off; off += (size_t)MTOK*FFD;    // fc raw; later pjpart[2]
  unsigned short* gello = (unsigned short*)(ws + off); off += (size_t)MTOK*FFD/2;

  unsigned short* qcod = (unsigned short*)x1rg;
  unsigned short* kcod = (unsigned short*)(x1rg + (size_t)MTOK*DD/2);
  float* x1 = x1rg;
  float* opart = qkvb;                       // 2 x [4096x1024]
  unsigned short* gelhi = (unsigned short*)qkvb;
  float* pjpart = fcb;                       // 2 x [4096x1024]

  const int ND  = MTOK*DD/4;
  const int NF  = MTOK*FFD/4;
  const int NW  = DD*DD/4;
  const int NWF = DD*FFD/4;

  auto g4 = [](int n4){ int g = (n4 + 255) / 256; return g > 4096 ? 4096 : g; };

  k_init<<<1, 64, 0, stream>>>(scal);
  k_bcat<<<12, 256, 0, stream>>>(bq, bk, bv, bcat);

  k_absmax<<<1024, 256, 0, stream>>>(wq,  NW,  scal+0);
  k_absmax<<<1024, 256, 0, stream>>>(wk,  NW,  scal+1);
  k_absmax<<<1024, 256, 0, stream>>>(wv,  NW,  scal+2);
  k_absmax<<<1024, 256, 0, stream>>>(wo,  NW,  scal+3);
  k_absmax<<<2048, 256, 0, stream>>>(wfc, NWF, scal+4);
  k_absmax<<<2048, 256, 0, stream>>>(wpj, NWF, scal+5);

  k_quantw_bf<<<g4(NW),  256, 0, stream>>>(wq,  wcatQ,                NW,  scal+0);
  k_quantw_bf<<<g4(NW),  256, 0, stream>>>(wk,  wcatQ + (size_t)DD*DD,   NW,  scal+1);
  k_quantw_bf<<<g4(NW),  256, 0, stream>>>(wv,  wcatQ + (size_t)2*DD*DD, NW,  scal+2);
  k_quantw_bf<<<g4(NW),  256, 0, stream>>>(wo,  woQ,  NW,  scal+3);
  k_quantw_bf<<<g4(NWF), 256, 0, stream>>>(wfc, wfcQ, NWF, scal+4);
  k_quantw_bf<<<g4(NWF), 256, 0, stream>>>(wpj, wpjQ, NWF, scal+5);

  k_ln_bf<<<MTOK, 256, 0, stream>>>(x, ln1g, ln1b, abhi, ablo);

  // fused q,k,v GEMM: N=3072, obs pairs at scal+6 (seg = col0>>10)
  k_gemm_bf<<<dim3(24, 32, 1), 256, 0, stream>>>(abhi, ablo, wcatQ, bcat, scal+0, scal+6,
                                                 qkvb, 3072, DD, DD, 10, 0);

  k_quant_codes<<<g4(ND), 256, 0, stream>>>(qkvb, 0,    qcod, scal+6);
  k_quant_codes<<<g4(ND), 256, 0, stream>>>(qkvb, 1024, kcod, scal+8);
  k_quant_codes_vt<<<dim3(8, 16, 8), 256, 0, stream>>>(qkvb, vtc, scal+10);

  k_attn_a_mfma<<<dim3(8, 16, 8), 256, 0, stream>>>(qcod, kcod, scal+6, scal+8,
                                                    rowm, rowz, scal+18);
  k_attn_b_mfma<<<dim3(8, 16, 8), 256, 0, stream>>>(qcod, kcod, vtc, scal+6, scal+8, scal+10,
                                                    rowm, rowz, scal+18, abhi, ablo);

  // o GEMM split-K x2 (no bias/obs in kernel)
  k_gemm_bf<<<dim3(8, 32, 2), 256, 0, stream>>>(abhi, ablo, woQ, nullptr, scal+3, nullptr,
                                                opart, DD, DD, 512, 20, (size_t)MTOK*DD);
  k_sum_minmax<<<2048, 256, 0, stream>>>(opart, opart + (size_t)MTOK*DD, bo, ND, 255, scal+19);
  k_quant_res2<<<g4(ND), 256, 0, stream>>>(opart, opart + (size_t)MTOK*DD, bo, x, x1, ND, 255, scal+19);

  k_ln_bf<<<MTOK, 256, 0, stream>>>(x1, ln2g, ln2b, abhi, ablo);

  // fc GEMM: N=4096, fused bias+obs
  k_gemm_bf<<<dim3(32, 32, 1), 256, 0, stream>>>(abhi, ablo, wfcQ, bfc, scal+4, scal+21,
                                                 fcb, FFD, DD, DD, 20, 0);
  k_gelu_codes<<<g4(NF), 256, 0, stream>>>(fcb, gelhi, gello, NF, scal+21);

  // pj GEMM split-K x2 over K=4096
  k_gemm_bf<<<dim3(8, 32, 2), 256, 0, stream>>>(gelhi, gello, wpjQ, nullptr, scal+5, nullptr,
                                                pjpart, DD, FFD, 2048, 20, (size_t)MTOK*DD);
  k_sum_minmax<<<2048, 256, 0, stream>>>(pjpart, pjpart + (size_t)MTOK*DD, bpj, ND, 255, scal+23);
  k_quant_res2<<<g4(ND), 256, 0, stream>>>(pjpart, pjpart + (size_t)MTOK*DD, bpj, x1, out, ND, 255, scal+23);
}

// Round 5
// 757.754 us; speedup vs baseline: 3.7206x; 1.0536x over previous
//
#include <hip/hip_runtime.h>
#include <cmath>

#define BB 8
#define LL 512
#define DD 1024
#define HH 16
#define HDD 64
#define FFD 4096
#define MTOK (BB*LL)
#define EPSF 1e-5f
#define BK 32

typedef __attribute__((ext_vector_type(8))) short bf16x8;
typedef __attribute__((ext_vector_type(4))) float f32x4;

// scal slots: 0..5 weight absmax (q,k,v,o,fc,pj)
// 6,7 q obs | 8,9 k | 10,11 v | 18 maxp | 19,20 o | 21,22 fc | 23,24 pj

__device__ inline void atomicMaxPos(float* addr, float v) {
  atomicMax((unsigned int*)addr, __float_as_uint(v));  // v >= 0, slot init 0
}

__device__ inline unsigned short f2bf(float x) {  // RNE to bf16 bits
  unsigned int u = __float_as_uint(x);
  u += 0x7fffu + ((u >> 16) & 1u);
  return (unsigned short)(u >> 16);
}
__device__ inline float bf2f(unsigned short h) {
  return __uint_as_float((unsigned int)h << 16);
}

// async 16B global->LDS (DMA; LDS dest is wave-uniform base + lane*16 by construction)
__device__ __forceinline__ void gld16(const unsigned short* g, unsigned short* l) {
  __builtin_amdgcn_global_load_lds(
      (const __attribute__((address_space(1))) unsigned int*)g,
      (__attribute__((address_space(3))) unsigned int*)l, 16, 0, 0);
}

__global__ void k_init(float* __restrict__ s) { s[threadIdx.x] = 0.0f; }

__global__ void k_bcat(const float* __restrict__ b0, const float* __restrict__ b1,
                       const float* __restrict__ b2, float* __restrict__ dst) {
  int i = blockIdx.x * blockDim.x + threadIdx.x;
  if (i < 3072) dst[i] = i < 1024 ? b0[i] : (i < 2048 ? b1[i - 1024] : b2[i - 2048]);
}

__global__ void k_absmax(const float* __restrict__ w, int n4, float* __restrict__ slot) {
  const float4* w4 = (const float4*)w;
  float m = 0.0f;
  for (int i = blockIdx.x * blockDim.x + threadIdx.x; i < n4; i += gridDim.x * blockDim.x) {
    float4 v = w4[i];
    m = fmaxf(m, fmaxf(fmaxf(fabsf(v.x), fabsf(v.y)), fmaxf(fabsf(v.z), fabsf(v.w))));
  }
  #pragma unroll
  for (int o = 32; o; o >>= 1) m = fmaxf(m, __shfl_down(m, o, 64));
  __shared__ float sb[4];
  int lane = threadIdx.x & 63, wid = threadIdx.x >> 6;
  if (lane == 0) sb[wid] = m;
  __syncthreads();
  if (threadIdx.x == 0) atomicMaxPos(slot, fmaxf(fmaxf(sb[0], sb[1]), fmaxf(sb[2], sb[3])));
}

__global__ void k_quantw_bf(const float* __restrict__ w, unsigned short* __restrict__ wq, int n4,
                            const float* __restrict__ slot) {
  float s = fmaxf(*slot / 127.0f, 1e-8f);
  const float4* w4 = (const float4*)w;
  ushort4* q4 = (ushort4*)wq;
  for (int i = blockIdx.x * blockDim.x + threadIdx.x; i < n4; i += gridDim.x * blockDim.x) {
    float4 v = w4[i];
    ushort4 o;
    o.x = f2bf(fminf(fmaxf(rintf(v.x / s), -128.0f), 127.0f));
    o.y = f2bf(fminf(fmaxf(rintf(v.y / s), -128.0f), 127.0f));
    o.z = f2bf(fminf(fmaxf(rintf(v.z / s), -128.0f), 127.0f));
    o.w = f2bf(fminf(fmaxf(rintf(v.w / s), -128.0f), 127.0f));
    q4[i] = o;
  }
}

__device__ inline float2 fq_params(const float* sHi, const float* sNeg) {
  float hi = *sHi, lo = -(*sNeg);
  float scale = fmaxf((hi - lo) / 255.0f, 1e-8f);
  float zp = rintf(-lo / scale);
  return make_float2(scale, zp);
}
__device__ inline float fq1(float x, float scale, float zp) {
  float q = fminf(fmaxf(rintf(x / scale) + zp, 0.0f), 255.0f);
  return (q - zp) * scale;
}
__device__ inline float2 fq_params2(const float* sHi, const float* sNeg) {
  float2 p1 = fq_params(sHi, sNeg);
  float hi2 = fq1(*sHi, p1.x, p1.y);
  float lo2 = fq1(-(*sNeg), p1.x, p1.y);
  float scale = fmaxf((hi2 - lo2) / 255.0f, 1e-8f);
  float zp = rintf(-lo2 / scale);
  return make_float2(scale, zp);
}
__device__ inline float code2(float x, float2 p1, float2 p2) {
  float v1 = fq1(x, p1.x, p1.y);
  float q = fminf(fmaxf(rintf(v1 / p2.x) + p2.y, 0.0f), 255.0f);
  return q - p2.y;
}

// raw qkv (ld 3072) -> double-fq -> bf16 integer codes packed [4096][1024]
__global__ void k_quant_codes(const float* __restrict__ src, int colBase,
                              unsigned short* __restrict__ oc, const float* __restrict__ sl) {
  float2 p1 = fq_params(sl, sl + 1);
  float2 p2 = fq_params2(sl, sl + 1);
  const int n4 = MTOK * DD / 4;
  for (int i = blockIdx.x * blockDim.x + threadIdx.x; i < n4; i += gridDim.x * blockDim.x) {
    int row = i >> 8, c = (i & 255) * 4;
    float4 v = *(const float4*)(src + (size_t)row * 3072 + colBase + c);
    ushort4 o;
    o.x = f2bf(code2(v.x, p1, p2)); o.y = f2bf(code2(v.y, p1, p2));
    o.z = f2bf(code2(v.z, p1, p2)); o.w = f2bf(code2(v.w, p1, p2));
    *(ushort4*)&oc[(size_t)row * DD + c] = o;
  }
}

// V codes per-head transposed: vt[((b*H+h)*64+d)*512 + m]; src ld 3072, col base 2048
__global__ __launch_bounds__(256) void k_quant_codes_vt(
    const float* __restrict__ src, unsigned short* __restrict__ vt,
    const float* __restrict__ sl) {
  __shared__ unsigned short tile[64 * 68];
  float2 p1 = fq_params(sl, sl + 1);
  float2 p2 = fq_params2(sl, sl + 1);
  const int m0 = blockIdx.x * 64, h = blockIdx.y, b = blockIdx.z;
  const int t = threadIdx.x;
  const int r = t >> 2, c0 = (t & 3) * 16;
  const float* s4 = src + ((size_t)(b * LL + m0 + r)) * 3072 + 2048 + h * HDD + c0;
  #pragma unroll
  for (int i = 0; i < 4; ++i) {
    float4 v = *(const float4*)(s4 + i * 4);
    ushort4 o;
    o.x = f2bf(code2(v.x, p1, p2)); o.y = f2bf(code2(v.y, p1, p2));
    o.z = f2bf(code2(v.z, p1, p2)); o.w = f2bf(code2(v.w, p1, p2));
    *(ushort4*)&tile[r * 68 + c0 + i * 4] = o;
  }
  __syncthreads();
  const int dr = t >> 2, ms = (t & 3) * 16;
  unsigned short* dst = vt + ((size_t)((b * HH + h) * HDD + dr)) * LL + m0 + ms;
  #pragma unroll
  for (int i = 0; i < 4; ++i) {
    ushort4 o;
    o.x = tile[(ms + i * 4 + 0) * 68 + dr];
    o.y = tile[(ms + i * 4 + 1) * 68 + dr];
    o.z = tile[(ms + i * 4 + 2) * 68 + dr];
    o.w = tile[(ms + i * 4 + 3) * 68 + dr];
    *(ushort4*)(dst + i * 4) = o;
  }
}

// lin = sum(parts) + bias -> minmax observer
__global__ void k_sum_minmax(const float* __restrict__ parts, size_t pstride4, int np,
                             const float* __restrict__ bias, int n4, int cmask,
                             float* __restrict__ sl) {
  float hi = 0.0f, ng = 0.0f;
  for (int i = blockIdx.x * blockDim.x + threadIdx.x; i < n4; i += gridDim.x * blockDim.x) {
    float4 bc = *(const float4*)(bias + (i & cmask) * 4);
    float vx = bc.x, vy = bc.y, vz = bc.z, vw = bc.w;
    for (int j = 0; j < np; ++j) {
      float4 a = ((const float4*)parts)[j * pstride4 + i];
      vx += a.x; vy += a.y; vz += a.z; vw += a.w;
    }
    hi = fmaxf(hi, fmaxf(fmaxf(vx, vy), fmaxf(vz, vw)));
    ng = fmaxf(ng, fmaxf(fmaxf(-vx, -vy), fmaxf(-vz, -vw)));
  }
  #pragma unroll
  for (int o = 32; o; o >>= 1) {
    hi = fmaxf(hi, __shfl_down(hi, o, 64));
    ng = fmaxf(ng, __shfl_down(ng, o, 64));
  }
  __shared__ float sh[4], sn[4];
  int lane = threadIdx.x & 63, wid = threadIdx.x >> 6;
  if (lane == 0) { sh[wid] = hi; sn[wid] = ng; }
  __syncthreads();
  if (threadIdx.x == 0) {
    atomicMaxPos(sl, fmaxf(fmaxf(sh[0], sh[1]), fmaxf(sh[2], sh[3])));
    atomicMaxPos(sl + 1, fmaxf(fmaxf(sn[0], sn[1]), fmaxf(sn[2], sn[3])));
  }
}

// out = res + fq(sum(parts)+bias)
__global__ void k_quant_res2(const float* __restrict__ parts, size_t pstride4, int np,
                             const float* __restrict__ bias, const float* __restrict__ res,
                             float* __restrict__ out, int n4, int cmask,
                             const float* __restrict__ sl) {
  float2 p = fq_params(sl, sl + 1);
  for (int i = blockIdx.x * blockDim.x + threadIdx.x; i < n4; i += gridDim.x * blockDim.x) {
    float4 bc = *(const float4*)(bias + (i & cmask) * 4);
    float vx = bc.x, vy = bc.y, vz = bc.z, vw = bc.w;
    for (int j = 0; j < np; ++j) {
      float4 a = ((const float4*)parts)[j * pstride4 + i];
      vx += a.x; vy += a.y; vz += a.z; vw += a.w;
    }
    float4 r = ((const float4*)res)[i];
    float4 o;
    o.x = r.x + fq1(vx, p.x, p.y);
    o.y = r.y + fq1(vy, p.x, p.y);
    o.z = r.z + fq1(vz, p.x, p.y);
    o.w = r.w + fq1(vw, p.x, p.y);
    ((float4*)out)[i] = o;
  }
}

__device__ inline float gelu_exact(float g) {
  return 0.5f * g * (1.0f + erff(g * 0.7071067811865475f));
}

// fc raw -> gelu(fq(.)) -> bf16 hi/lo
__global__ void k_gelu_codes(const float* __restrict__ x,
                             unsigned short* __restrict__ ghi, unsigned short* __restrict__ glo,
                             int n4, const float* __restrict__ sl) {
  float2 p = fq_params(sl, sl + 1);
  for (int i = blockIdx.x * blockDim.x + threadIdx.x; i < n4; i += gridDim.x * blockDim.x) {
    float4 v = ((const float4*)x)[i];
    float g0 = gelu_exact(fq1(v.x, p.x, p.y)), g1 = gelu_exact(fq1(v.y, p.x, p.y));
    float g2 = gelu_exact(fq1(v.z, p.x, p.y)), g3 = gelu_exact(fq1(v.w, p.x, p.y));
    ushort4 h, l;
    h.x = f2bf(g0); l.x = f2bf(g0 - bf2f(h.x));
    h.y = f2bf(g1); l.y = f2bf(g1 - bf2f(h.y));
    h.z = f2bf(g2); l.z = f2bf(g2 - bf2f(h.z));
    h.w = f2bf(g3); l.w = f2bf(g3 - bf2f(h.w));
    ((ushort4*)ghi)[i] = h;
    ((ushort4*)glo)[i] = l;
  }
}

__device__ inline float block_sum256(float v, float* sb) {
  #pragma unroll
  for (int o = 32; o; o >>= 1) v += __shfl_down(v, o, 64);
  int lane = threadIdx.x & 63, wid = threadIdx.x >> 6;
  __syncthreads();
  if (lane == 0) sb[wid] = v;
  __syncthreads();
  return sb[0] + sb[1] + sb[2] + sb[3];
}

// LayerNorm -> bf16 hi/lo pair
__global__ __launch_bounds__(256) void k_ln_bf(const float* __restrict__ x, const float* __restrict__ g,
                                               const float* __restrict__ bta,
                                               unsigned short* __restrict__ ohi,
                                               unsigned short* __restrict__ olo) {
  __shared__ float sb[4];
  int row = blockIdx.x;
  const float4* xr = (const float4*)(x + (size_t)row * DD);
  float4 v = xr[threadIdx.x];
  float mu = block_sum256(v.x + v.y + v.z + v.w, sb) * (1.0f / DD);
  float dx = v.x - mu, dy = v.y - mu, dz = v.z - mu, dw = v.w - mu;
  float var = block_sum256(dx*dx + dy*dy + dz*dz + dw*dw, sb) * (1.0f / DD);
  float rs = 1.0f / sqrtf(var + EPSF);
  float4 gv = ((const float4*)g)[threadIdx.x];
  float4 bv = ((const float4*)bta)[threadIdx.x];
  float o0 = dx * rs * gv.x + bv.x;
  float o1 = dy * rs * gv.y + bv.y;
  float o2 = dz * rs * gv.z + bv.z;
  float o3 = dw * rs * gv.w + bv.w;
  ushort4 h, l;
  h.x = f2bf(o0); l.x = f2bf(o0 - bf2f(h.x));
  h.y = f2bf(o1); l.y = f2bf(o1 - bf2f(h.y));
  h.z = f2bf(o2); l.z = f2bf(o2 - bf2f(h.z));
  h.w = f2bf(o3); l.w = f2bf(o3 - bf2f(h.w));
  ((ushort4*)(ohi + (size_t)row * DD))[threadIdx.x] = h;
  ((ushort4*)(olo + (size_t)row * DD))[threadIdx.x] = l;
}

// MFMA GEMM, pre-split bf16 A (hi/lo) x bf16 weight codes.
// blockIdx.x = ROW tile (XCD locality: each XCD keeps its 4 A row-tiles in L2),
// blockIdx.y = col tile, blockIdx.z = split-K part.
// Staging via async global_load_lds (16B) into unpadded LDS with XOR chunk swizzle
// (chunk ^= (row>>1)&3) -> ds_read_b128 lands exactly 2-way per bank (free).
__global__ __launch_bounds__(256, 3) void k_gemm_bf(
    const unsigned short* __restrict__ Ahi, const unsigned short* __restrict__ Alo,
    const unsigned short* __restrict__ Bq,
    const float* __restrict__ bias, const float* __restrict__ wsc, float* __restrict__ obs,
    float* __restrict__ C, int ldC, int K, int kLen, int segShift, size_t partStride) {
  __shared__ unsigned short sAh[128 * BK];
  __shared__ unsigned short sAl[128 * BK];
  __shared__ unsigned short sB [128 * BK];
  __shared__ float redH, redN;
  const int t = threadIdx.x;
  const int row0 = blockIdx.x * 128, col0 = blockIdx.y * 128;
  const int kOff = blockIdx.z * kLen;
  float* Cp = C + (size_t)blockIdx.z * partStride;
  const int wave = t >> 6, lane = t & 63;
  const int wr = (wave >> 1) * 64, wc = (wave & 1) * 64;
  const int fr = lane & 15, fq = lane >> 4;
  const int seg = col0 >> segShift;
  const float s = fmaxf(wsc[seg] / 127.0f, 1e-8f);
  if (t == 0) { redH = 0.f; redN = 0.f; }

  f32x4 acc[4][4];
  #pragma unroll
  for (int i = 0; i < 4; ++i)
    #pragma unroll
    for (int j = 0; j < 4; ++j) acc[i][j] = (f32x4){0.f, 0.f, 0.f, 0.f};

  // staging geometry: wave w, issue i covers rows (w*2+i)*16 .. +15 (16 rows x 64B = 1KB)
  const int srB = lane >> 2;          // row within 16-row group
  const int scs = lane & 3;           // LDS chunk slot (16B units)

  for (int k0 = kOff; k0 < kOff + kLen; k0 += BK) {
    __syncthreads();
    #pragma unroll
    for (int it = 0; it < 2; ++it) {
      int r = (wave * 2 + it) * 16 + srB;
      int g = scs ^ ((r >> 1) & 3);                 // global chunk for this LDS slot
      size_t ga = (size_t)(row0 + r) * K + k0 + g * 8;
      size_t gb = (size_t)(col0 + r) * K + k0 + g * 8;
      int ld = r * BK + scs * 8;
      gld16(Ahi + ga, &sAh[ld]);
      gld16(Alo + ga, &sAl[ld]);
      gld16(Bq + gb, &sB[ld]);
    }
    __syncthreads();
    bf16x8 ah[4], al[4], bb[4];
    #pragma unroll
    for (int i = 0; i < 4; ++i) {
      int Ra = wr + i * 16 + fr;
      int Rb = wc + i * 16 + fr;
      ah[i] = *(const bf16x8*)&sAh[Ra * BK + ((fq ^ ((Ra >> 1) & 3)) * 8)];
      al[i] = *(const bf16x8*)&sAl[Ra * BK + ((fq ^ ((Ra >> 1) & 3)) * 8)];
      bb[i] = *(const bf16x8*)&sB [Rb * BK + ((fq ^ ((Rb >> 1) & 3)) * 8)];
    }
    #pragma unroll
    for (int i = 0; i < 4; ++i)
      #pragma unroll
      for (int j = 0; j < 4; ++j) {
        acc[i][j] = __builtin_amdgcn_mfma_f32_16x16x32_bf16(ah[i], bb[j], acc[i][j], 0, 0, 0);
        acc[i][j] = __builtin_amdgcn_mfma_f32_16x16x32_bf16(al[i], bb[j], acc[i][j], 0, 0, 0);
      }
  }

  float ohi = 0.f, ong = 0.f;
  #pragma unroll
  for (int i = 0; i < 4; ++i) {
    #pragma unroll
    for (int j = 0; j < 4; ++j) {
      int col = col0 + wc + j * 16 + fr;
      float bcol = bias ? bias[col] : 0.0f;
      #pragma unroll
      for (int rg = 0; rg < 4; ++rg) {
        int row = row0 + wr + i * 16 + fq * 4 + rg;
        float val = acc[i][j][rg] * s + bcol;
        if (obs) { ohi = fmaxf(ohi, val); ong = fmaxf(ong, -val); }
        Cp[(size_t)row * ldC + col] = val;
      }
    }
  }
  if (obs) {
    #pragma unroll
    for (int o = 32; o; o >>= 1) {
      ohi = fmaxf(ohi, __shfl_down(ohi, o, 64));
      ong = fmaxf(ong, __shfl_down(ong, o, 64));
    }
    if (lane == 0) { atomicMaxPos(&redH, ohi); atomicMaxPos(&redN, ong); }
    __syncthreads();
    if (t == 0) {
      atomicMaxPos(obs + 2 * seg, redH);
      atomicMaxPos(obs + 2 * seg + 1, redN);
    }
  }
}

// ---- MFMA attention on integer bf16 codes ----
__global__ __launch_bounds__(256) void k_attn_a_mfma(
    const unsigned short* __restrict__ qc, const unsigned short* __restrict__ kc,
    const float* __restrict__ slq, const float* __restrict__ slk,
    float* __restrict__ rowm, float* __restrict__ rowz, float* __restrict__ maxp) {
  __shared__ unsigned short ks[64 * 72];
  __shared__ float redp;
  const int t = threadIdx.x, wave = t >> 6, lane = t & 63;
  const int fr = lane & 15, fq = lane >> 4;
  const int l0 = blockIdx.x * 64, h = blockIdx.y, b = blockIdx.z;
  const float sfac = fq_params2(slq, slq + 1).x * fq_params2(slk, slk + 1).x * 0.125f;
  if (t == 0) redp = 0.f;
  const unsigned short* qrow = qc + ((size_t)(b * LL + l0 + wave * 16 + fr)) * DD + h * HDD;
  bf16x8 qa0 = *(const bf16x8*)(qrow + fq * 8);
  bf16x8 qa1 = *(const bf16x8*)(qrow + 32 + fq * 8);
  float mrun[4] = {-INFINITY, -INFINITY, -INFINITY, -INFINITY};
  float zrun[4] = {0.f, 0.f, 0.f, 0.f};
  for (int mc = 0; mc < LL; mc += 64) {
    __syncthreads();
    #pragma unroll
    for (int it = 0; it < 2; ++it) {
      int si = t + it * 256, r = si >> 3, c8 = (si & 7) * 8;
      *(bf16x8*)&ks[r * 72 + c8] =
          *(const bf16x8*)(kc + ((size_t)(b * LL + mc + r)) * DD + h * HDD + c8);
    }
    __syncthreads();
    float sv[4][4];
    #pragma unroll
    for (int j = 0; j < 4; ++j) {
      bf16x8 b0 = *(const bf16x8*)&ks[(j * 16 + fr) * 72 + fq * 8];
      bf16x8 b1 = *(const bf16x8*)&ks[(j * 16 + fr) * 72 + 32 + fq * 8];
      f32x4 sAcc = (f32x4){0.f, 0.f, 0.f, 0.f};
      sAcc = __builtin_amdgcn_mfma_f32_16x16x32_bf16(qa0, b0, sAcc, 0, 0, 0);
      sAcc = __builtin_amdgcn_mfma_f32_16x16x32_bf16(qa1, b1, sAcc, 0, 0, 0);
      #pragma unroll
      for (int rg = 0; rg < 4; ++rg) sv[j][rg] = sAcc[rg] * sfac;
    }
    #pragma unroll
    for (int rg = 0; rg < 4; ++rg) {
      float nm = mrun[rg];
      #pragma unroll
      for (int j = 0; j < 4; ++j) nm = fmaxf(nm, sv[j][rg]);
      float z = zrun[rg] * expf(mrun[rg] - nm);
      #pragma unroll
      for (int j = 0; j < 4; ++j) z += expf(sv[j][rg] - nm);
      zrun[rg] = z; mrun[rg] = nm;
    }
  }
  #pragma unroll
  for (int off = 1; off < 16; off <<= 1) {
    #pragma unroll
    for (int rg = 0; rg < 4; ++rg) {
      float om = __shfl_xor(mrun[rg], off, 64);
      float oz = __shfl_xor(zrun[rg], off, 64);
      float nm = fmaxf(mrun[rg], om);
      zrun[rg] = zrun[rg] * expf(mrun[rg] - nm) + oz * expf(om - nm);
      mrun[rg] = nm;
    }
  }
  if (fr == 0) {
    int rid = (b * HH + h) * LL + l0 + wave * 16 + fq * 4;
    float lmax = 0.f;
    #pragma unroll
    for (int rg = 0; rg < 4; ++rg) {
      rowm[rid + rg] = mrun[rg]; rowz[rid + rg] = zrun[rg];
      lmax = fmaxf(lmax, 1.0f / zrun[rg]);
    }
    atomicMaxPos(&redp, lmax);
  }
  __syncthreads();
  if (t == 0) atomicMaxPos(maxp, redp);
}

__global__ __launch_bounds__(256) void k_attn_b_mfma(
    const unsigned short* __restrict__ qc, const unsigned short* __restrict__ kc,
    const unsigned short* __restrict__ vt,
    const float* __restrict__ slq, const float* __restrict__ slk, const float* __restrict__ slv,
    const float* __restrict__ rowm, const float* __restrict__ rowz,
    const float* __restrict__ maxp,
    unsigned short* __restrict__ chi, unsigned short* __restrict__ clo) {
  __shared__ unsigned short ks[64 * 72];
  __shared__ unsigned short vs[64 * 72];
  __shared__ unsigned short ps[4][16 * 72];
  const int t = threadIdx.x, wave = t >> 6, lane = t & 63;
  const int fr = lane & 15, fq = lane >> 4;
  const int l0 = blockIdx.x * 64, h = blockIdx.y, b = blockIdx.z;
  const float sfac = fq_params2(slq, slq + 1).x * fq_params2(slk, slk + 1).x * 0.125f;
  const float sv2 = fq_params2(slv, slv + 1).x;
  const float pscale = fmaxf(maxp[0] / 255.0f, 1e-8f);
  const float ipscale = 1.0f / pscale;
  const int ridb = (b * HH + h) * LL + l0 + wave * 16 + fq * 4;
  float rm[4], rzi[4];
  #pragma unroll
  for (int rg = 0; rg < 4; ++rg) { rm[rg] = rowm[ridb + rg]; rzi[rg] = 1.0f / rowz[ridb + rg]; }
  const unsigned short* qrow = qc + ((size_t)(b * LL + l0 + wave * 16 + fr)) * DD + h * HDD;
  bf16x8 qa0 = *(const bf16x8*)(qrow + fq * 8);
  bf16x8 qa1 = *(const bf16x8*)(qrow + 32 + fq * 8);
  f32x4 acc[4];
  #pragma unroll
  for (int jd = 0; jd < 4; ++jd) acc[jd] = (f32x4){0.f, 0.f, 0.f, 0.f};

  for (int mc = 0; mc < LL; mc += 64) {
    __syncthreads();
    #pragma unroll
    for (int it = 0; it < 2; ++it) {
      int si = t + it * 256, r = si >> 3, c8 = (si & 7) * 8;
      *(bf16x8*)&ks[r * 72 + c8] =
          *(const bf16x8*)(kc + ((size_t)(b * LL + mc + r)) * DD + h * HDD + c8);
      *(bf16x8*)&vs[r * 72 + c8] =
          *(const bf16x8*)(vt + ((size_t)((b * HH + h) * HDD + r)) * LL + mc + c8);
    }
    __syncthreads();
    #pragma unroll
    for (int j = 0; j < 4; ++j) {
      bf16x8 b0 = *(const bf16x8*)&ks[(j * 16 + fr) * 72 + fq * 8];
      bf16x8 b1 = *(const bf16x8*)&ks[(j * 16 + fr) * 72 + 32 + fq * 8];
      f32x4 sAcc = (f32x4){0.f, 0.f, 0.f, 0.f};
      sAcc = __builtin_amdgcn_mfma_f32_16x16x32_bf16(qa0, b0, sAcc, 0, 0, 0);
      sAcc = __builtin_amdgcn_mfma_f32_16x16x32_bf16(qa1, b1, sAcc, 0, 0, 0);
      #pragma unroll
      for (int rg = 0; rg < 4; ++rg) {
        float p = expf(sAcc[rg] * sfac - rm[rg]) * rzi[rg];
        float q = fminf(fmaxf(rintf(p * ipscale), 0.0f), 255.0f);
        ps[wave][(fq * 4 + rg) * 72 + j * 16 + fr] = f2bf(q);
      }
    }
    __syncthreads();
    bf16x8 pa0 = *(const bf16x8*)&ps[wave][fr * 72 + fq * 8];
    bf16x8 pa1 = *(const bf16x8*)&ps[wave][fr * 72 + 32 + fq * 8];
    #pragma unroll
    for (int jd = 0; jd < 4; ++jd) {
      bf16x8 vb0 = *(const bf16x8*)&vs[(jd * 16 + fr) * 72 + fq * 8];
      bf16x8 vb1 = *(const bf16x8*)&vs[(jd * 16 + fr) * 72 + 32 + fq * 8];
      acc[jd] = __builtin_amdgcn_mfma_f32_16x16x32_bf16(pa0, vb0, acc[jd], 0, 0, 0);
      acc[jd] = __builtin_amdgcn_mfma_f32_16x16x32_bf16(pa1, vb1, acc[jd], 0, 0, 0);
    }
  }
  const float osc = pscale * sv2;
  #pragma unroll
  for (int jd = 0; jd < 4; ++jd)
    #pragma unroll
    for (int rg = 0; rg < 4; ++rg) {
      int row = l0 + wave * 16 + fq * 4 + rg;
      size_t cidx = ((size_t)(b * LL + row)) * DD + h * HDD + jd * 16 + fr;
      float val = acc[jd][rg] * osc;
      unsigned short hh = f2bf(val);
      chi[cidx] = hh;
      clo[cidx] = f2bf(val - bf2f(hh));
    }
}

extern "C" void kernel_launch(void* const* d_in, const int* in_sizes, int n_in,
                              void* d_out, int out_size, void* d_ws, size_t ws_size,
                              hipStream_t stream) {
  const float* x    = (const float*)d_in[0];
  const float* ln1g = (const float*)d_in[1];
  const float* ln1b = (const float*)d_in[2];
  const float* wq   = (const float*)d_in[3];
  const float* bq   = (const float*)d_in[4];
  const float* wk   = (const float*)d_in[5];
  const float* bk   = (const float*)d_in[6];
  const float* wv   = (const float*)d_in[7];
  const float* bv   = (const float*)d_in[8];
  const float* wo   = (const float*)d_in[9];
  const float* bo   = (const float*)d_in[10];
  const float* ln2g = (const float*)d_in[11];
  const float* ln2b = (const float*)d_in[12];
  const float* wfc  = (const float*)d_in[13];
  const float* bfc  = (const float*)d_in[14];
  const float* wpj  = (const float*)d_in[15];
  const float* bpj  = (const float*)d_in[16];
  float* out = (float*)d_out;
  float* ws = (float*)d_ws;

  size_t off = 0;
  float* scal = ws + off; off += 256;
  float* bcat = ws + off; off += 3072;
  unsigned short* wcatQ = (unsigned short*)(ws + off); off += (size_t)3072*DD/2;   // q,k,v stacked
  unsigned short* woQ   = (unsigned short*)(ws + off); off += (size_t)DD*DD/2;
  unsigned short* wfcQ  = (unsigned short*)(ws + off); off += (size_t)FFD*DD/2;
  unsigned short* wpjQ  = (unsigned short*)(ws + off); off += (size_t)DD*FFD/2;
  unsigned short* abhi  = (unsigned short*)(ws + off); off += (size_t)MTOK*DD/2;   // h1 -> ctx -> h2
  unsigned short* ablo  = (unsigned short*)(ws + off); off += (size_t)MTOK*DD/2;
  float* qkvb = ws + off; off += (size_t)MTOK*3072;   // raw qkv; later opart[2]; later gel hi/lo
  float* x1rg = ws + off; off += (size_t)MTOK*DD;     // first qcod+kcod; later x1
  unsigned short* vtc = (unsigned short*)(ws + off); off += (size_t)MTOK*DD/2;
  float* rowm = ws + off; off += (size_t)BB*HH*LL;
  float* rowz = ws + off; off += (size_t)BB*HH*LL;
  float* fcb  = ws + off; off += (size_t)MTOK*FFD;    // fc raw; later pjpart[4]
  unsigned short* gello = (unsigned short*)(ws + off); off += (size_t)MTOK*FFD/2;

  unsigned short* qcod = (unsigned short*)x1rg;
  unsigned short* kcod = (unsigned short*)(x1rg + (size_t)MTOK*DD/2);
  float* x1 = x1rg;
  float* opart = qkvb;                       // 2 x [4096x1024]
  unsigned short* gelhi = (unsigned short*)qkvb;
  float* pjpart = fcb;                       // 4 x [4096x1024]

  const int ND  = MTOK*DD/4;
  const int NF  = MTOK*FFD/4;
  const int NW  = DD*DD/4;
  const int NWF = DD*FFD/4;
  const size_t PS4 = (size_t)MTOK*DD/4;      // part stride in float4s

  auto g4 = [](int n4){ int g = (n4 + 255) / 256; return g > 4096 ? 4096 : g; };

  k_init<<<1, 64, 0, stream>>>(scal);
  k_bcat<<<12, 256, 0, stream>>>(bq, bk, bv, bcat);

  k_absmax<<<1024, 256, 0, stream>>>(wq,  NW,  scal+0);
  k_absmax<<<1024, 256, 0, stream>>>(wk,  NW,  scal+1);
  k_absmax<<<1024, 256, 0, stream>>>(wv,  NW,  scal+2);
  k_absmax<<<1024, 256, 0, stream>>>(wo,  NW,  scal+3);
  k_absmax<<<2048, 256, 0, stream>>>(wfc, NWF, scal+4);
  k_absmax<<<2048, 256, 0, stream>>>(wpj, NWF, scal+5);

  k_quantw_bf<<<g4(NW),  256, 0, stream>>>(wq,  wcatQ,                   NW,  scal+0);
  k_quantw_bf<<<g4(NW),  256, 0, stream>>>(wk,  wcatQ + (size_t)DD*DD,   NW,  scal+1);
  k_quantw_bf<<<g4(NW),  256, 0, stream>>>(wv,  wcatQ + (size_t)2*DD*DD, NW,  scal+2);
  k_quantw_bf<<<g4(NW),  256, 0, stream>>>(wo,  woQ,  NW,  scal+3);
  k_quantw_bf<<<g4(NWF), 256, 0, stream>>>(wfc, wfcQ, NWF, scal+4);
  k_quantw_bf<<<g4(NWF), 256, 0, stream>>>(wpj, wpjQ, NWF, scal+5);

  k_ln_bf<<<MTOK, 256, 0, stream>>>(x, ln1g, ln1b, abhi, ablo);

  // fused q,k,v GEMM: rows on x, cols on y; obs pairs at scal+6 (seg = col0>>10)
  k_gemm_bf<<<dim3(32, 24, 1), 256, 0, stream>>>(abhi, ablo, wcatQ, bcat, scal+0, scal+6,
                                                 qkvb, 3072, DD, DD, 10, 0);

  k_quant_codes<<<g4(ND), 256, 0, stream>>>(qkvb, 0,    qcod, scal+6);
  k_quant_codes<<<g4(ND), 256, 0, stream>>>(qkvb, 1024, kcod, scal+8);
  k_quant_codes_vt<<<dim3(8, 16, 8), 256, 0, stream>>>(qkvb, vtc, scal+10);

  k_attn_a_mfma<<<dim3(8, 16, 8), 256, 0, stream>>>(qcod, kcod, scal+6, scal+8,
                                                    rowm, rowz, scal+18);
  k_attn_b_mfma<<<dim3(8, 16, 8), 256, 0, stream>>>(qcod, kcod, vtc, scal+6, scal+8, scal+10,
                                                    rowm, rowz, scal+18, abhi, ablo);

  // o GEMM split-K x2
  k_gemm_bf<<<dim3(32, 8, 2), 256, 0, stream>>>(abhi, ablo, woQ, nullptr, scal+3, nullptr,
                                                opart, DD, DD, 512, 20, (size_t)MTOK*DD);
  k_sum_minmax<<<2048, 256, 0, stream>>>(opart, PS4, 2, bo, ND, 255, scal+19);
  k_quant_res2<<<g4(ND), 256, 0, stream>>>(opart, PS4, 2, bo, x, x1, ND, 255, scal+19);

  k_ln_bf<<<MTOK, 256, 0, stream>>>(x1, ln2g, ln2b, abhi, ablo);

  // fc GEMM: N=4096, fused bias+obs
  k_gemm_bf<<<dim3(32, 32, 1), 256, 0, stream>>>(abhi, ablo, wfcQ, bfc, scal+4, scal+21,
                                                 fcb, FFD, DD, DD, 20, 0);
  k_gelu_codes<<<g4(NF), 256, 0, stream>>>(fcb, gelhi, gello, NF, scal+21);

  // pj GEMM split-K x4 over K=4096
  k_gemm_bf<<<dim3(32, 8, 4), 256, 0, stream>>>(gelhi, gello, wpjQ, nullptr, scal+5, nullptr,
                                                pjpart, DD, FFD, 1024, 20, (size_t)MTOK*DD);
  k_sum_minmax<<<2048, 256, 0, stream>>>(pjpart, PS4, 4, bpj, ND, 255, scal+23);
  k_quant_res2<<<g4(ND), 256, 0, stream>>>(pjpart, PS4, 4, bpj, x1, out, ND, 255, scal+23);
}

// Round 6
// 620.895 us; speedup vs baseline: 4.5408x; 1.2204x over previous
//
#include <hip/hip_runtime.h>
#include <cmath>

#define BB 8
#define LL 512
#define DD 1024
#define HH 16
#define HDD 64
#define FFD 4096
#define MTOK (BB*LL)
#define EPSF 1e-5f
#define BK 64

typedef __attribute__((ext_vector_type(8))) short bf16x8;
typedef __attribute__((ext_vector_type(4))) float f32x4;

// scal slots: 0..5 weight absmax (q,k,v,o,fc,pj)
// 6,7 q obs | 8,9 k | 10,11 v | 18 maxp | 19,20 o | 21,22 fc | 23,24 pj

struct WSet {
  const float* w[6];
  unsigned short* q[6];
  int n4[6];
};

__device__ inline void atomicMaxPos(float* addr, float v) {
  atomicMax((unsigned int*)addr, __float_as_uint(v));  // v >= 0, slot init 0
}

__device__ inline unsigned short f2bf(float x) {  // RNE to bf16 bits
  unsigned int u = __float_as_uint(x);
  u += 0x7fffu + ((u >> 16) & 1u);
  return (unsigned short)(u >> 16);
}
__device__ inline float bf2f(unsigned short h) {
  return __uint_as_float((unsigned int)h << 16);
}

// async 16B global->LDS; dest addresses are base+lane*16 by construction
__device__ __forceinline__ void gld16(const unsigned short* g, unsigned short* l) {
  __builtin_amdgcn_global_load_lds(
      (const __attribute__((address_space(1))) unsigned int*)g,
      (__attribute__((address_space(3))) unsigned int*)l, 16, 0, 0);
}

__global__ void k_init_bcat(float* __restrict__ s, const float* __restrict__ b0,
                            const float* __restrict__ b1, const float* __restrict__ b2,
                            float* __restrict__ dst) {
  int i = blockIdx.x * blockDim.x + threadIdx.x;
  if (i < 256) s[i] = 0.0f;
  if (i < 3072) dst[i] = i < 1024 ? b0[i] : (i < 2048 ? b1[i - 1024] : b2[i - 2048]);
}

__global__ void k_absmax6(WSet ws, float* __restrict__ scal) {
  const int id = blockIdx.y;
  const float4* w4 = (const float4*)ws.w[id];
  const int n4 = ws.n4[id];
  float m = 0.0f;
  for (int i = blockIdx.x * blockDim.x + threadIdx.x; i < n4; i += gridDim.x * blockDim.x) {
    float4 v = w4[i];
    m = fmaxf(m, fmaxf(fmaxf(fabsf(v.x), fabsf(v.y)), fmaxf(fabsf(v.z), fabsf(v.w))));
  }
  #pragma unroll
  for (int o = 32; o; o >>= 1) m = fmaxf(m, __shfl_down(m, o, 64));
  __shared__ float sb[4];
  int lane = threadIdx.x & 63, wid = threadIdx.x >> 6;
  if (lane == 0) sb[wid] = m;
  __syncthreads();
  if (threadIdx.x == 0) atomicMaxPos(scal + id, fmaxf(fmaxf(sb[0], sb[1]), fmaxf(sb[2], sb[3])));
}

__global__ void k_quantw6(WSet ws, const float* __restrict__ scal) {
  const int id = blockIdx.y;
  float s = fmaxf(scal[id] / 127.0f, 1e-8f);
  const float4* w4 = (const float4*)ws.w[id];
  ushort4* q4 = (ushort4*)ws.q[id];
  const int n4 = ws.n4[id];
  for (int i = blockIdx.x * blockDim.x + threadIdx.x; i < n4; i += gridDim.x * blockDim.x) {
    float4 v = w4[i];
    ushort4 o;
    o.x = f2bf(fminf(fmaxf(rintf(v.x / s), -128.0f), 127.0f));
    o.y = f2bf(fminf(fmaxf(rintf(v.y / s), -128.0f), 127.0f));
    o.z = f2bf(fminf(fmaxf(rintf(v.z / s), -128.0f), 127.0f));
    o.w = f2bf(fminf(fmaxf(rintf(v.w / s), -128.0f), 127.0f));
    q4[i] = o;
  }
}

__device__ inline float2 fq_params(const float* sHi, const float* sNeg) {
  float hi = *sHi, lo = -(*sNeg);
  float scale = fmaxf((hi - lo) / 255.0f, 1e-8f);
  float zp = rintf(-lo / scale);
  return make_float2(scale, zp);
}
__device__ inline float fq1(float x, float scale, float zp) {
  float q = fminf(fmaxf(rintf(x / scale) + zp, 0.0f), 255.0f);
  return (q - zp) * scale;
}
__device__ inline float2 fq_params2(const float* sHi, const float* sNeg) {
  float2 p1 = fq_params(sHi, sNeg);
  float hi2 = fq1(*sHi, p1.x, p1.y);
  float lo2 = fq1(-(*sNeg), p1.x, p1.y);
  float scale = fmaxf((hi2 - lo2) / 255.0f, 1e-8f);
  float zp = rintf(-lo2 / scale);
  return make_float2(scale, zp);
}
__device__ inline float code2(float x, float2 p1, float2 p2) {
  float v1 = fq1(x, p1.x, p1.y);
  float q = fminf(fmaxf(rintf(v1 / p2.x) + p2.y, 0.0f), 255.0f);
  return q - p2.y;
}

// raw qkv (ld 3072) -> double-fq -> bf16 integer codes packed [4096][1024]
__global__ void k_quant_codes(const float* __restrict__ src, int colBase,
                              unsigned short* __restrict__ oc, const float* __restrict__ sl) {
  float2 p1 = fq_params(sl, sl + 1);
  float2 p2 = fq_params2(sl, sl + 1);
  const int n4 = MTOK * DD / 4;
  for (int i = blockIdx.x * blockDim.x + threadIdx.x; i < n4; i += gridDim.x * blockDim.x) {
    int row = i >> 8, c = (i & 255) * 4;
    float4 v = *(const float4*)(src + (size_t)row * 3072 + colBase + c);
    ushort4 o;
    o.x = f2bf(code2(v.x, p1, p2)); o.y = f2bf(code2(v.y, p1, p2));
    o.z = f2bf(code2(v.z, p1, p2)); o.w = f2bf(code2(v.w, p1, p2));
    *(ushort4*)&oc[(size_t)row * DD + c] = o;
  }
}

// V codes per-head transposed: vt[((b*H+h)*64+d)*512 + m]; src ld 3072, col base 2048
__global__ __launch_bounds__(256) void k_quant_codes_vt(
    const float* __restrict__ src, unsigned short* __restrict__ vt,
    const float* __restrict__ sl) {
  __shared__ unsigned short tile[64 * 68];
  float2 p1 = fq_params(sl, sl + 1);
  float2 p2 = fq_params2(sl, sl + 1);
  const int m0 = blockIdx.x * 64, h = blockIdx.y, b = blockIdx.z;
  const int t = threadIdx.x;
  const int r = t >> 2, c0 = (t & 3) * 16;
  const float* s4 = src + ((size_t)(b * LL + m0 + r)) * 3072 + 2048 + h * HDD + c0;
  #pragma unroll
  for (int i = 0; i < 4; ++i) {
    float4 v = *(const float4*)(s4 + i * 4);
    ushort4 o;
    o.x = f2bf(code2(v.x, p1, p2)); o.y = f2bf(code2(v.y, p1, p2));
    o.z = f2bf(code2(v.z, p1, p2)); o.w = f2bf(code2(v.w, p1, p2));
    *(ushort4*)&tile[r * 68 + c0 + i * 4] = o;
  }
  __syncthreads();
  const int dr = t >> 2, ms = (t & 3) * 16;
  unsigned short* dst = vt + ((size_t)((b * HH + h) * HDD + dr)) * LL + m0 + ms;
  #pragma unroll
  for (int i = 0; i < 4; ++i) {
    ushort4 o;
    o.x = tile[(ms + i * 4 + 0) * 68 + dr];
    o.y = tile[(ms + i * 4 + 1) * 68 + dr];
    o.z = tile[(ms + i * 4 + 2) * 68 + dr];
    o.w = tile[(ms + i * 4 + 3) * 68 + dr];
    *(ushort4*)(dst + i * 4) = o;
  }
}

// lin = sum(parts) + bias -> minmax observer
__global__ void k_sum_minmax(const float* __restrict__ parts, size_t pstride4, int np,
                             const float* __restrict__ bias, int n4, int cmask,
                             float* __restrict__ sl) {
  float hi = 0.0f, ng = 0.0f;
  for (int i = blockIdx.x * blockDim.x + threadIdx.x; i < n4; i += gridDim.x * blockDim.x) {
    float4 bc = *(const float4*)(bias + (i & cmask) * 4);
    float vx = bc.x, vy = bc.y, vz = bc.z, vw = bc.w;
    for (int j = 0; j < np; ++j) {
      float4 a = ((const float4*)parts)[j * pstride4 + i];
      vx += a.x; vy += a.y; vz += a.z; vw += a.w;
    }
    hi = fmaxf(hi, fmaxf(fmaxf(vx, vy), fmaxf(vz, vw)));
    ng = fmaxf(ng, fmaxf(fmaxf(-vx, -vy), fmaxf(-vz, -vw)));
  }
  #pragma unroll
  for (int o = 32; o; o >>= 1) {
    hi = fmaxf(hi, __shfl_down(hi, o, 64));
    ng = fmaxf(ng, __shfl_down(ng, o, 64));
  }
  __shared__ float sh[4], sn[4];
  int lane = threadIdx.x & 63, wid = threadIdx.x >> 6;
  if (lane == 0) { sh[wid] = hi; sn[wid] = ng; }
  __syncthreads();
  if (threadIdx.x == 0) {
    atomicMaxPos(sl, fmaxf(fmaxf(sh[0], sh[1]), fmaxf(sh[2], sh[3])));
    atomicMaxPos(sl + 1, fmaxf(fmaxf(sn[0], sn[1]), fmaxf(sn[2], sn[3])));
  }
}

// out = res + fq(sum(parts)+bias)
__global__ void k_quant_res2(const float* __restrict__ parts, size_t pstride4, int np,
                             const float* __restrict__ bias, const float* __restrict__ res,
                             float* __restrict__ out, int n4, int cmask,
                             const float* __restrict__ sl) {
  float2 p = fq_params(sl, sl + 1);
  for (int i = blockIdx.x * blockDim.x + threadIdx.x; i < n4; i += gridDim.x * blockDim.x) {
    float4 bc = *(const float4*)(bias + (i & cmask) * 4);
    float vx = bc.x, vy = bc.y, vz = bc.z, vw = bc.w;
    for (int j = 0; j < np; ++j) {
      float4 a = ((const float4*)parts)[j * pstride4 + i];
      vx += a.x; vy += a.y; vz += a.z; vw += a.w;
    }
    float4 r = ((const float4*)res)[i];
    float4 o;
    o.x = r.x + fq1(vx, p.x, p.y);
    o.y = r.y + fq1(vy, p.x, p.y);
    o.z = r.z + fq1(vz, p.x, p.y);
    o.w = r.w + fq1(vw, p.x, p.y);
    ((float4*)out)[i] = o;
  }
}

__device__ inline float gelu_exact(float g) {
  return 0.5f * g * (1.0f + erff(g * 0.7071067811865475f));
}

// fc raw -> gelu(fq(.)) -> bf16 hi/lo
__global__ void k_gelu_codes(const float* __restrict__ x,
                             unsigned short* __restrict__ ghi, unsigned short* __restrict__ glo,
                             int n4, const float* __restrict__ sl) {
  float2 p = fq_params(sl, sl + 1);
  for (int i = blockIdx.x * blockDim.x + threadIdx.x; i < n4; i += gridDim.x * blockDim.x) {
    float4 v = ((const float4*)x)[i];
    float g0 = gelu_exact(fq1(v.x, p.x, p.y)), g1 = gelu_exact(fq1(v.y, p.x, p.y));
    float g2 = gelu_exact(fq1(v.z, p.x, p.y)), g3 = gelu_exact(fq1(v.w, p.x, p.y));
    ushort4 h, l;
    h.x = f2bf(g0); l.x = f2bf(g0 - bf2f(h.x));
    h.y = f2bf(g1); l.y = f2bf(g1 - bf2f(h.y));
    h.z = f2bf(g2); l.z = f2bf(g2 - bf2f(h.z));
    h.w = f2bf(g3); l.w = f2bf(g3 - bf2f(h.w));
    ((ushort4*)ghi)[i] = h;
    ((ushort4*)glo)[i] = l;
  }
}

__device__ inline float block_sum256(float v, float* sb) {
  #pragma unroll
  for (int o = 32; o; o >>= 1) v += __shfl_down(v, o, 64);
  int lane = threadIdx.x & 63, wid = threadIdx.x >> 6;
  __syncthreads();
  if (lane == 0) sb[wid] = v;
  __syncthreads();
  return sb[0] + sb[1] + sb[2] + sb[3];
}

// LayerNorm -> bf16 hi/lo pair
__global__ __launch_bounds__(256) void k_ln_bf(const float* __restrict__ x, const float* __restrict__ g,
                                               const float* __restrict__ bta,
                                               unsigned short* __restrict__ ohi,
                                               unsigned short* __restrict__ olo) {
  __shared__ float sb[4];
  int row = blockIdx.x;
  const float4* xr = (const float4*)(x + (size_t)row * DD);
  float4 v = xr[threadIdx.x];
  float mu = block_sum256(v.x + v.y + v.z + v.w, sb) * (1.0f / DD);
  float dx = v.x - mu, dy = v.y - mu, dz = v.z - mu, dw = v.w - mu;
  float var = block_sum256(dx*dx + dy*dy + dz*dz + dw*dw, sb) * (1.0f / DD);
  float rs = 1.0f / sqrtf(var + EPSF);
  float4 gv = ((const float4*)g)[threadIdx.x];
  float4 bv = ((const float4*)bta)[threadIdx.x];
  float o0 = dx * rs * gv.x + bv.x;
  float o1 = dy * rs * gv.y + bv.y;
  float o2 = dz * rs * gv.z + bv.z;
  float o3 = dw * rs * gv.w + bv.w;
  ushort4 h, l;
  h.x = f2bf(o0); l.x = f2bf(o0 - bf2f(h.x));
  h.y = f2bf(o1); l.y = f2bf(o1 - bf2f(h.y));
  h.z = f2bf(o2); l.z = f2bf(o2 - bf2f(h.z));
  h.w = f2bf(o3); l.w = f2bf(o3 - bf2f(h.w));
  ((ushort4*)(ohi + (size_t)row * DD))[threadIdx.x] = h;
  ((ushort4*)(olo + (size_t)row * DD))[threadIdx.x] = l;
}

// fused: x1 = res + fq(p0+p1+bias), then LayerNorm(x1) -> bf16 hi/lo (one block per row)
__global__ __launch_bounds__(256) void k_res_ln(
    const float* __restrict__ parts, size_t pstride4,
    const float* __restrict__ bias, const float* __restrict__ res,
    float* __restrict__ x1, const float* __restrict__ sl,
    const float* __restrict__ g, const float* __restrict__ bta,
    unsigned short* __restrict__ ohi, unsigned short* __restrict__ olo) {
  __shared__ float sb[4];
  float2 p = fq_params(sl, sl + 1);
  int row = blockIdx.x, t = threadIdx.x;
  size_t i4 = (size_t)row * 256 + t;
  float4 a = ((const float4*)parts)[i4];
  float4 b = ((const float4*)parts)[pstride4 + i4];
  float4 bc = ((const float4*)bias)[t];
  float4 r = ((const float4*)res)[i4];
  float4 xv;
  xv.x = r.x + fq1(a.x + b.x + bc.x, p.x, p.y);
  xv.y = r.y + fq1(a.y + b.y + bc.y, p.x, p.y);
  xv.z = r.z + fq1(a.z + b.z + bc.z, p.x, p.y);
  xv.w = r.w + fq1(a.w + b.w + bc.w, p.x, p.y);
  ((float4*)x1)[i4] = xv;
  float mu = block_sum256(xv.x + xv.y + xv.z + xv.w, sb) * (1.0f / DD);
  float dx = xv.x - mu, dy = xv.y - mu, dz = xv.z - mu, dw = xv.w - mu;
  float var = block_sum256(dx*dx + dy*dy + dz*dz + dw*dw, sb) * (1.0f / DD);
  float rs = 1.0f / sqrtf(var + EPSF);
  float4 gv = ((const float4*)g)[t];
  float4 bv = ((const float4*)bta)[t];
  float o0 = dx * rs * gv.x + bv.x;
  float o1 = dy * rs * gv.y + bv.y;
  float o2 = dz * rs * gv.z + bv.z;
  float o3 = dw * rs * gv.w + bv.w;
  ushort4 h, l;
  h.x = f2bf(o0); l.x = f2bf(o0 - bf2f(h.x));
  h.y = f2bf(o1); l.y = f2bf(o1 - bf2f(h.y));
  h.z = f2bf(o2); l.z = f2bf(o2 - bf2f(h.z));
  h.w = f2bf(o3); l.w = f2bf(o3 - bf2f(h.w));
  ((ushort4*)(ohi + (size_t)row * DD))[t] = h;
  ((ushort4*)(olo + (size_t)row * DD))[t] = l;
}

// MFMA GEMM, pre-split bf16 A (hi/lo) x bf16 weight codes. BK=64 (64 MFMAs/barrier/wave).
// blockIdx.x = ROW tile (XCD L2 pinning), y = col tile, z = split-K part.
// Staging: async global_load_lds 16B; LDS dest = base+lane*16 (contiguous).
// 8-chunk XOR swizzle c = chunk ^ (row&7): rows with equal logical chunk spread
// over all 8 chunk positions -> ds_read_b128 is exactly 2-way (free).
__global__ __launch_bounds__(256, 3) void k_gemm_bf(
    const unsigned short* __restrict__ Ahi, const unsigned short* __restrict__ Alo,
    const unsigned short* __restrict__ Bq,
    const float* __restrict__ bias, const float* __restrict__ wsc, float* __restrict__ obs,
    float* __restrict__ C, int ldC, int K, int kLen, int segShift, size_t partStride) {
  __shared__ unsigned short sAh[128 * BK];
  __shared__ unsigned short sAl[128 * BK];
  __shared__ unsigned short sB [128 * BK];
  __shared__ float redH, redN;
  const int t = threadIdx.x;
  const int row0 = blockIdx.x * 128, col0 = blockIdx.y * 128;
  const int kOff = blockIdx.z * kLen;
  float* Cp = C + (size_t)blockIdx.z * partStride;
  const int wave = t >> 6, lane = t & 63;
  const int wr = (wave >> 1) * 64, wc = (wave & 1) * 64;
  const int fr = lane & 15, fq = lane >> 4;
  const int seg = col0 >> segShift;
  const float s = fmaxf(wsc[seg] / 127.0f, 1e-8f);
  if (t == 0) { redH = 0.f; redN = 0.f; }

  f32x4 acc[4][4];
  #pragma unroll
  for (int i = 0; i < 4; ++i)
    #pragma unroll
    for (int j = 0; j < 4; ++j) acc[i][j] = (f32x4){0.f, 0.f, 0.f, 0.f};

  const int srB = lane >> 3;          // row within 8-row group
  const int scs = lane & 7;           // LDS chunk slot (16B units, 8 per row)

  for (int k0 = kOff; k0 < kOff + kLen; k0 += BK) {
    __syncthreads();
    #pragma unroll
    for (int it = 0; it < 4; ++it) {
      int r = (wave * 4 + it) * 8 + srB;
      int g = scs ^ (r & 7);                        // global chunk for this LDS slot
      size_t ga = (size_t)(row0 + r) * K + k0 + g * 8;
      size_t gb = (size_t)(col0 + r) * K + k0 + g * 8;
      int ld = r * BK + scs * 8;
      gld16(Ahi + ga, &sAh[ld]);
      gld16(Alo + ga, &sAl[ld]);
      gld16(Bq + gb, &sB[ld]);
    }
    __syncthreads();
    #pragma unroll
    for (int hh = 0; hh < 2; ++hh) {
      bf16x8 ah[4], al[4], bb[4];
      #pragma unroll
      for (int i = 0; i < 4; ++i) {
        int Ra = wr + i * 16 + fr;
        int Rb = wc + i * 16 + fr;
        int ca = ((hh * 4 + fq) ^ (Ra & 7)) * 8;
        int cb = ((hh * 4 + fq) ^ (Rb & 7)) * 8;
        ah[i] = *(const bf16x8*)&sAh[Ra * BK + ca];
        al[i] = *(const bf16x8*)&sAl[Ra * BK + ca];
        bb[i] = *(const bf16x8*)&sB [Rb * BK + cb];
      }
      #pragma unroll
      for (int i = 0; i < 4; ++i)
        #pragma unroll
        for (int j = 0; j < 4; ++j) {
          acc[i][j] = __builtin_amdgcn_mfma_f32_16x16x32_bf16(ah[i], bb[j], acc[i][j], 0, 0, 0);
          acc[i][j] = __builtin_amdgcn_mfma_f32_16x16x32_bf16(al[i], bb[j], acc[i][j], 0, 0, 0);
        }
    }
  }

  float ohi = 0.f, ong = 0.f;
  #pragma unroll
  for (int i = 0; i < 4; ++i) {
    #pragma unroll
    for (int j = 0; j < 4; ++j) {
      int col = col0 + wc + j * 16 + fr;
      float bcol = bias ? bias[col] : 0.0f;
      #pragma unroll
      for (int rg = 0; rg < 4; ++rg) {
        int row = row0 + wr + i * 16 + fq * 4 + rg;
        float val = acc[i][j][rg] * s + bcol;
        if (obs) { ohi = fmaxf(ohi, val); ong = fmaxf(ong, -val); }
        Cp[(size_t)row * ldC + col] = val;
      }
    }
  }
  if (obs) {
    #pragma unroll
    for (int o = 32; o; o >>= 1) {
      ohi = fmaxf(ohi, __shfl_down(ohi, o, 64));
      ong = fmaxf(ong, __shfl_down(ong, o, 64));
    }
    if (lane == 0) { atomicMaxPos(&redH, ohi); atomicMaxPos(&redN, ong); }
    __syncthreads();
    if (t == 0) {
      atomicMaxPos(obs + 2 * seg, redH);
      atomicMaxPos(obs + 2 * seg + 1, redN);
    }
  }
}

// ---- MFMA attention on integer bf16 codes ----
__global__ __launch_bounds__(256) void k_attn_a_mfma(
    const unsigned short* __restrict__ qc, const unsigned short* __restrict__ kc,
    const float* __restrict__ slq, const float* __restrict__ slk,
    float* __restrict__ rowm, float* __restrict__ rowz, float* __restrict__ maxp) {
  __shared__ unsigned short ks[64 * 72];
  __shared__ float redp;
  const int t = threadIdx.x, wave = t >> 6, lane = t & 63;
  const int fr = lane & 15, fq = lane >> 4;
  const int l0 = blockIdx.x * 64, h = blockIdx.y, b = blockIdx.z;
  const float sfac = fq_params2(slq, slq + 1).x * fq_params2(slk, slk + 1).x * 0.125f;
  if (t == 0) redp = 0.f;
  const unsigned short* qrow = qc + ((size_t)(b * LL + l0 + wave * 16 + fr)) * DD + h * HDD;
  bf16x8 qa0 = *(const bf16x8*)(qrow + fq * 8);
  bf16x8 qa1 = *(const bf16x8*)(qrow + 32 + fq * 8);
  float mrun[4] = {-INFINITY, -INFINITY, -INFINITY, -INFINITY};
  float zrun[4] = {0.f, 0.f, 0.f, 0.f};
  for (int mc = 0; mc < LL; mc += 64) {
    __syncthreads();
    #pragma unroll
    for (int it = 0; it < 2; ++it) {
      int si = t + it * 256, r = si >> 3, c8 = (si & 7) * 8;
      *(bf16x8*)&ks[r * 72 + c8] =
          *(const bf16x8*)(kc + ((size_t)(b * LL + mc + r)) * DD + h * HDD + c8);
    }
    __syncthreads();
    float sv[4][4];
    #pragma unroll
    for (int j = 0; j < 4; ++j) {
      bf16x8 b0 = *(const bf16x8*)&ks[(j * 16 + fr) * 72 + fq * 8];
      bf16x8 b1 = *(const bf16x8*)&ks[(j * 16 + fr) * 72 + 32 + fq * 8];
      f32x4 sAcc = (f32x4){0.f, 0.f, 0.f, 0.f};
      sAcc = __builtin_amdgcn_mfma_f32_16x16x32_bf16(qa0, b0, sAcc, 0, 0, 0);
      sAcc = __builtin_amdgcn_mfma_f32_16x16x32_bf16(qa1, b1, sAcc, 0, 0, 0);
      #pragma unroll
      for (int rg = 0; rg < 4; ++rg) sv[j][rg] = sAcc[rg] * sfac;
    }
    #pragma unroll
    for (int rg = 0; rg < 4; ++rg) {
      float nm = mrun[rg];
      #pragma unroll
      for (int j = 0; j < 4; ++j) nm = fmaxf(nm, sv[j][rg]);
      float z = zrun[rg] * expf(mrun[rg] - nm);
      #pragma unroll
      for (int j = 0; j < 4; ++j) z += expf(sv[j][rg] - nm);
      zrun[rg] = z; mrun[rg] = nm;
    }
  }
  #pragma unroll
  for (int off = 1; off < 16; off <<= 1) {
    #pragma unroll
    for (int rg = 0; rg < 4; ++rg) {
      float om = __shfl_xor(mrun[rg], off, 64);
      float oz = __shfl_xor(zrun[rg], off, 64);
      float nm = fmaxf(mrun[rg], om);
      zrun[rg] = zrun[rg] * expf(mrun[rg] - nm) + oz * expf(om - nm);
      mrun[rg] = nm;
    }
  }
  if (fr == 0) {
    int rid = (b * HH + h) * LL + l0 + wave * 16 + fq * 4;
    float lmax = 0.f;
    #pragma unroll
    for (int rg = 0; rg < 4; ++rg) {
      rowm[rid + rg] = mrun[rg]; rowz[rid + rg] = zrun[rg];
      lmax = fmaxf(lmax, 1.0f / zrun[rg]);
    }
    atomicMaxPos(&redp, lmax);
  }
  __syncthreads();
  if (t == 0) atomicMaxPos(maxp, redp);
}

__global__ __launch_bounds__(256) void k_attn_b_mfma(
    const unsigned short* __restrict__ qc, const unsigned short* __restrict__ kc,
    const unsigned short* __restrict__ vt,
    const float* __restrict__ slq, const float* __restrict__ slk, const float* __restrict__ slv,
    const float* __restrict__ rowm, const float* __restrict__ rowz,
    const float* __restrict__ maxp,
    unsigned short* __restrict__ chi, unsigned short* __restrict__ clo) {
  __shared__ unsigned short ks[64 * 72];
  __shared__ unsigned short vs[64 * 72];
  __shared__ unsigned short ps[4][16 * 72];
  const int t = threadIdx.x, wave = t >> 6, lane = t & 63;
  const int fr = lane & 15, fq = lane >> 4;
  const int l0 = blockIdx.x * 64, h = blockIdx.y, b = blockIdx.z;
  const float sfac = fq_params2(slq, slq + 1).x * fq_params2(slk, slk + 1).x * 0.125f;
  const float sv2 = fq_params2(slv, slv + 1).x;
  const float pscale = fmaxf(maxp[0] / 255.0f, 1e-8f);
  const float ipscale = 1.0f / pscale;
  const int ridb = (b * HH + h) * LL + l0 + wave * 16 + fq * 4;
  float rm[4], rzi[4];
  #pragma unroll
  for (int rg = 0; rg < 4; ++rg) { rm[rg] = rowm[ridb + rg]; rzi[rg] = 1.0f / rowz[ridb + rg]; }
  const unsigned short* qrow = qc + ((size_t)(b * LL + l0 + wave * 16 + fr)) * DD + h * HDD;
  bf16x8 qa0 = *(const bf16x8*)(qrow + fq * 8);
  bf16x8 qa1 = *(const bf16x8*)(qrow + 32 + fq * 8);
  f32x4 acc[4];
  #pragma unroll
  for (int jd = 0; jd < 4; ++jd) acc[jd] = (f32x4){0.f, 0.f, 0.f, 0.f};

  for (int mc = 0; mc < LL; mc += 64) {
    __syncthreads();
    #pragma unroll
    for (int it = 0; it < 2; ++it) {
      int si = t + it * 256, r = si >> 3, c8 = (si & 7) * 8;
      *(bf16x8*)&ks[r * 72 + c8] =
          *(const bf16x8*)(kc + ((size_t)(b * LL + mc + r)) * DD + h * HDD + c8);
      *(bf16x8*)&vs[r * 72 + c8] =
          *(const bf16x8*)(vt + ((size_t)((b * HH + h) * HDD + r)) * LL + mc + c8);
    }
    __syncthreads();
    #pragma unroll
    for (int j = 0; j < 4; ++j) {
      bf16x8 b0 = *(const bf16x8*)&ks[(j * 16 + fr) * 72 + fq * 8];
      bf16x8 b1 = *(const bf16x8*)&ks[(j * 16 + fr) * 72 + 32 + fq * 8];
      f32x4 sAcc = (f32x4){0.f, 0.f, 0.f, 0.f};
      sAcc = __builtin_amdgcn_mfma_f32_16x16x32_bf16(qa0, b0, sAcc, 0, 0, 0);
      sAcc = __builtin_amdgcn_mfma_f32_16x16x32_bf16(qa1, b1, sAcc, 0, 0, 0);
      #pragma unroll
      for (int rg = 0; rg < 4; ++rg) {
        float p = expf(sAcc[rg] * sfac - rm[rg]) * rzi[rg];
        float q = fminf(fmaxf(rintf(p * ipscale), 0.0f), 255.0f);
        ps[wave][(fq * 4 + rg) * 72 + j * 16 + fr] = f2bf(q);
      }
    }
    __syncthreads();
    bf16x8 pa0 = *(const bf16x8*)&ps[wave][fr * 72 + fq * 8];
    bf16x8 pa1 = *(const bf16x8*)&ps[wave][fr * 72 + 32 + fq * 8];
    #pragma unroll
    for (int jd = 0; jd < 4; ++jd) {
      bf16x8 vb0 = *(const bf16x8*)&vs[(jd * 16 + fr) * 72 + fq * 8];
      bf16x8 vb1 = *(const bf16x8*)&vs[(jd * 16 + fr) * 72 + 32 + fq * 8];
      acc[jd] = __builtin_amdgcn_mfma_f32_16x16x32_bf16(pa0, vb0, acc[jd], 0, 0, 0);
      acc[jd] = __builtin_amdgcn_mfma_f32_16x16x32_bf16(pa1, vb1, acc[jd], 0, 0, 0);
    }
  }
  const float osc = pscale * sv2;
  #pragma unroll
  for (int jd = 0; jd < 4; ++jd)
    #pragma unroll
    for (int rg = 0; rg < 4; ++rg) {
      int row = l0 + wave * 16 + fq * 4 + rg;
      size_t cidx = ((size_t)(b * LL + row)) * DD + h * HDD + jd * 16 + fr;
      float val = acc[jd][rg] * osc;
      unsigned short hh = f2bf(val);
      chi[cidx] = hh;
      clo[cidx] = f2bf(val - bf2f(hh));
    }
}

extern "C" void kernel_launch(void* const* d_in, const int* in_sizes, int n_in,
                              void* d_out, int out_size, void* d_ws, size_t ws_size,
                              hipStream_t stream) {
  const float* x    = (const float*)d_in[0];
  const float* ln1g = (const float*)d_in[1];
  const float* ln1b = (const float*)d_in[2];
  const float* wq   = (const float*)d_in[3];
  const float* bq   = (const float*)d_in[4];
  const float* wk   = (const float*)d_in[5];
  const float* bk   = (const float*)d_in[6];
  const float* wv   = (const float*)d_in[7];
  const float* bv   = (const float*)d_in[8];
  const float* wo   = (const float*)d_in[9];
  const float* bo   = (const float*)d_in[10];
  const float* ln2g = (const float*)d_in[11];
  const float* ln2b = (const float*)d_in[12];
  const float* wfc  = (const float*)d_in[13];
  const float* bfc  = (const float*)d_in[14];
  const float* wpj  = (const float*)d_in[15];
  const float* bpj  = (const float*)d_in[16];
  float* out = (float*)d_out;
  float* ws = (float*)d_ws;

  size_t off = 0;
  float* scal = ws + off; off += 256;
  float* bcat = ws + off; off += 3072;
  unsigned short* wcatQ = (unsigned short*)(ws + off); off += (size_t)3072*DD/2;   // q,k,v stacked
  unsigned short* woQ   = (unsigned short*)(ws + off); off += (size_t)DD*DD/2;
  unsigned short* wfcQ  = (unsigned short*)(ws + off); off += (size_t)FFD*DD/2;
  unsigned short* wpjQ  = (unsigned short*)(ws + off); off += (size_t)DD*FFD/2;
  unsigned short* abhi  = (unsigned short*)(ws + off); off += (size_t)MTOK*DD/2;   // h1 -> ctx -> h2
  unsigned short* ablo  = (unsigned short*)(ws + off); off += (size_t)MTOK*DD/2;
  float* qkvb = ws + off; off += (size_t)MTOK*3072;   // raw qkv; later opart[2]; later gel hi
  float* x1rg = ws + off; off += (size_t)MTOK*DD;     // first qcod+kcod; later x1
  unsigned short* vtc = (unsigned short*)(ws + off); off += (size_t)MTOK*DD/2;
  float* rowm = ws + off; off += (size_t)BB*HH*LL;
  float* rowz = ws + off; off += (size_t)BB*HH*LL;
  float* fcb  = ws + off; off += (size_t)MTOK*FFD;    // fc raw; later pjpart[2]
  unsigned short* gello = (unsigned short*)(ws + off); off += (size_t)MTOK*FFD/2;

  unsigned short* qcod = (unsigned short*)x1rg;
  unsigned short* kcod = (unsigned short*)(x1rg + (size_t)MTOK*DD/2);
  float* x1 = x1rg;
  float* opart = qkvb;                       // 2 x [4096x1024]
  unsigned short* gelhi = (unsigned short*)qkvb;
  float* pjpart = fcb;                       // 2 x [4096x1024]

  const int ND  = MTOK*DD/4;
  const int NF  = MTOK*FFD/4;
  const int NW  = DD*DD/4;
  const int NWF = DD*FFD/4;
  const size_t PS4 = (size_t)MTOK*DD/4;      // part stride in float4s

  auto g4 = [](int n4){ int g = (n4 + 255) / 256; return g > 4096 ? 4096 : g; };

  k_init_bcat<<<12, 256, 0, stream>>>(scal, bq, bk, bv, bcat);

  WSet wset;
  wset.w[0] = wq;  wset.q[0] = wcatQ;                   wset.n4[0] = NW;
  wset.w[1] = wk;  wset.q[1] = wcatQ + (size_t)DD*DD;   wset.n4[1] = NW;
  wset.w[2] = wv;  wset.q[2] = wcatQ + (size_t)2*DD*DD; wset.n4[2] = NW;
  wset.w[3] = wo;  wset.q[3] = woQ;                     wset.n4[3] = NW;
  wset.w[4] = wfc; wset.q[4] = wfcQ;                    wset.n4[4] = NWF;
  wset.w[5] = wpj; wset.q[5] = wpjQ;                    wset.n4[5] = NWF;

  k_absmax6<<<dim3(512, 6), 256, 0, stream>>>(wset, scal);
  k_quantw6<<<dim3(512, 6), 256, 0, stream>>>(wset, scal);

  k_ln_bf<<<MTOK, 256, 0, stream>>>(x, ln1g, ln1b, abhi, ablo);

  // fused q,k,v GEMM: rows on x, cols on y; obs pairs at scal+6 (seg = col0>>10)
  k_gemm_bf<<<dim3(32, 24, 1), 256, 0, stream>>>(abhi, ablo, wcatQ, bcat, scal+0, scal+6,
                                                 qkvb, 3072, DD, DD, 10, 0);

  k_quant_codes<<<g4(ND), 256, 0, stream>>>(qkvb, 0,    qcod, scal+6);
  k_quant_codes<<<g4(ND), 256, 0, stream>>>(qkvb, 1024, kcod, scal+8);
  k_quant_codes_vt<<<dim3(8, 16, 8), 256, 0, stream>>>(qkvb, vtc, scal+10);

  k_attn_a_mfma<<<dim3(8, 16, 8), 256, 0, stream>>>(qcod, kcod, scal+6, scal+8,
                                                    rowm, rowz, scal+18);
  k_attn_b_mfma<<<dim3(8, 16, 8), 256, 0, stream>>>(qcod, kcod, vtc, scal+6, scal+8, scal+10,
                                                    rowm, rowz, scal+18, abhi, ablo);

  // o GEMM split-K x2
  k_gemm_bf<<<dim3(32, 8, 2), 256, 0, stream>>>(abhi, ablo, woQ, nullptr, scal+3, nullptr,
                                                opart, DD, DD, 512, 20, (size_t)MTOK*DD);
  k_sum_minmax<<<2048, 256, 0, stream>>>(opart, PS4, 2, bo, ND, 255, scal+19);
  // fused residual + LN2 -> x1 + h2 hi/lo
  k_res_ln<<<MTOK, 256, 0, stream>>>(opart, PS4, bo, x, x1, scal+19,
                                     ln2g, ln2b, abhi, ablo);

  // fc GEMM: N=4096, fused bias+obs
  k_gemm_bf<<<dim3(32, 32, 1), 256, 0, stream>>>(abhi, ablo, wfcQ, bfc, scal+4, scal+21,
                                                 fcb, FFD, DD, DD, 20, 0);
  k_gelu_codes<<<g4(NF), 256, 0, stream>>>(fcb, gelhi, gello, NF, scal+21);

  // pj GEMM split-K x2 over K=4096
  k_gemm_bf<<<dim3(32, 8, 2), 256, 0, stream>>>(gelhi, gello, wpjQ, nullptr, scal+5, nullptr,
                                                pjpart, DD, FFD, 2048, 20, (size_t)MTOK*DD);
  k_sum_minmax<<<2048, 256, 0, stream>>>(pjpart, PS4, 2, bpj, ND, 255, scal+23);
  k_quant_res2<<<g4(ND), 256, 0, stream>>>(pjpart, PS4, 2, bpj, x1, out, ND, 255, scal+23);
}